// Round 3
// baseline (12960.172 us; speedup 1.0000x reference)
//
#include <hip/hip_runtime.h>

// ---------------------------------------------------------------------------
// TGCN2 forward, MI355X gfx950. R13: INTRA-BLOCK RECURRENCE.
// R10/R12 showed the per-step cost is the loop-carried cross-XCD LLC hop
// (~4us/step regardless of flag vs payload sync). The GRU recurrence is
// batch-independent and only channel-coupled, so the channel-split (16
// blocks/layer exchanging h every step) is the structural mistake.
// New structure:
//   - L0, L1 = ONE block each (8 waves). Full Whh (256x768, f16) lives in
//     VGPRs (192 regs/wave). h state ping-pongs in LDS (hstage[2][64][256]
//     f16, 64KB) -> per-step exchange is intra-CU, 1 barrier/step.
//   - Non-recurrent input halves stream in as FORWARD edges (latency
//     hideable): 8 feeder blocks compute GI0 = x@Wih0^T+b, 8 helper blocks
//     compute GI1 = h0seq@Wih1^T+b. 64-slot rings + monotonic stamps +
//     progress-counter throttling (SLACK=56) -> consumer polls first-try.
//   - State/weights f16 (h bounded by 1; f16 8x finer than bf16 - needed
//     since fp32 hreg doesn't fit registers anymore).
// TGCN branch unchanged, on side stream (R7). Math identities unchanged.
// ---------------------------------------------------------------------------

typedef unsigned short u16;
typedef unsigned long long u64;
typedef short s8v __attribute__((ext_vector_type(8)));
typedef _Float16 h8v __attribute__((ext_vector_type(8)));
typedef float f4v __attribute__((ext_vector_type(4)));

#define NBATCH 64
#define NNODE  512
#define DCIN   128
#define DHID   256
#define NEDGE  8192
#define RSLOT  64
#define SLACK  56

#define AT_LD(p)   __hip_atomic_load((p), __ATOMIC_RELAXED, __HIP_MEMORY_SCOPE_AGENT)
#define AT_ST(p,v) __hip_atomic_store((p), (v), __ATOMIC_RELAXED, __HIP_MEMORY_SCOPE_AGENT)

__device__ __forceinline__ u16 f2b(float f) {
    union { float f; unsigned int i; } v; v.f = f;
    unsigned int x = v.i;
    return (u16)((x + 0x7FFFu + ((x >> 16) & 1u)) >> 16);   // RNE (TGCN path)
}
__device__ __forceinline__ float sigm(float x)  { return 1.0f / (1.0f + __expf(-x)); }
__device__ __forceinline__ float tanh_(float x) { return 1.0f - 2.0f / (1.0f + __expf(2.0f * x)); }
__device__ __forceinline__ f4v mfma16(s8v a, s8v b, f4v c) {
    return __builtin_amdgcn_mfma_f32_16x16x32_bf16(a, b, c, 0, 0, 0);
}
__device__ __forceinline__ f4v mfma16h(h8v a, h8v b, f4v c) {
    return __builtin_amdgcn_mfma_f32_16x16x32_f16(a, b, c, 0, 0, 0);
}
__device__ __forceinline__ f4v ld_ring_f4(const u64* p) {
    union { u64 d[2]; f4v v; } u;
    u.d[0] = AT_LD(p); u.d[1] = AT_LD(p + 1);
    return u.v;
}
__device__ __forceinline__ void st_ring_f4(u64* p, f4v v) {
    union { f4v v; u64 d[2]; } u; u.v = v;
    AT_ST(p, u.d[0]); AT_ST(p + 1, u.d[1]);
}
__device__ __forceinline__ h8v ld_ring_h8(const u64* p) {
    union { u64 d[2]; h8v v; } u;
    u.d[0] = AT_LD(p); u.d[1] = AT_LD(p + 1);
    return u.v;
}
__device__ __forceinline__ void st_ring_h8(u64* p, h8v v) {
    union { h8v v; u64 d[2]; } u; u.v = v;
    AT_ST(p, u.d[0]); AT_ST(p + 1, u.d[1]);
}
__device__ __forceinline__ u16 f2h_bits(float f) {
    _Float16 h = (_Float16)f;
    return __builtin_bit_cast(u16, h);
}

// --------------------------- graph preprocessing ---------------------------
__global__ void init_kernel(float* deg, int* counts, int* syncb) {
    int i = blockIdx.x * blockDim.x + threadIdx.x;
    if (i < NNODE) { deg[i] = 2.0f; counts[i] = 1; }
    if (i < 2048) syncb[i] = -1;   // prog/progH/stamps: must be < 0
}

__global__ void edge_deg_kernel(const int* __restrict__ ei, const float* __restrict__ ew,
                                float* deg, int* counts) {
    int e = blockIdx.x * blockDim.x + threadIdx.x;
    if (e < NEDGE) {
        int t = ei[NEDGE + e];
        atomicAdd(&deg[t], ew[e]);
        atomicAdd(&counts[t], 1);
    }
}

__global__ void scan_kernel(const float* __restrict__ deg, const int* __restrict__ counts,
                            float* __restrict__ dinv, int* __restrict__ rowptr,
                            int* __restrict__ cursor, int* __restrict__ col,
                            float* __restrict__ val) {
    __shared__ int sc[NNODE];
    int i = threadIdx.x;
    float d = deg[i];
    float di = (d > 0.0f) ? (1.0f / sqrtf(d)) : 0.0f;
    dinv[i] = di;
    int cnt = counts[i];
    sc[i] = cnt;
    __syncthreads();
    for (int ofs = 1; ofs < NNODE; ofs <<= 1) {
        int add = (i >= ofs) ? sc[i - ofs] : 0;
        __syncthreads();
        sc[i] += add;
        __syncthreads();
    }
    int ex = sc[i] - cnt;
    rowptr[i] = ex;
    if (i == NNODE - 1) rowptr[NNODE] = sc[NNODE - 1];
    col[ex] = i;
    val[ex] = di * 2.0f * di;
    cursor[i] = ex + 1;
}

__global__ void fill_kernel(const int* __restrict__ ei, const float* __restrict__ ew,
                            const float* __restrict__ dinv, int* cursor,
                            int* __restrict__ col, float* __restrict__ val) {
    int e = blockIdx.x * blockDim.x + threadIdx.x;
    if (e < NEDGE) {
        int s = ei[e], t = ei[NEDGE + e];
        int p = atomicAdd(&cursor[t], 1);
        col[p] = s;
        val[p] = dinv[s] * ew[e] * dinv[t];
    }
}

// Wf[2j+g][k] = sum_m Wg[k][m]*Lg_top[m][j]; bfold[2j+g] = bg@Lg_top[:,j]+lgb[j]
__global__ void fold_kernel(const float* __restrict__ Wz, const float* __restrict__ lzW,
                            const float* __restrict__ bz, const float* __restrict__ lzb,
                            const float* __restrict__ Wh, const float* __restrict__ lhW,
                            const float* __restrict__ bh, const float* __restrict__ lhb,
                            u16* __restrict__ Wf, float* __restrict__ bfold) {
    int nidx = blockIdx.x;
    int g = nidx & 1, j = nidx >> 1;
    int k = threadIdx.x;
    const float* W = g ? Wh : Wz;
    const float* L = g ? lhW : lzW;
    float acc = 0.0f;
    for (int m = 0; m < DHID; ++m)
        acc += W[k * DHID + m] * L[m * DHID + j];
    Wf[nidx * DCIN + k] = f2b(acc);
    if (k == 0) {
        const float* bg = g ? bh : bz;
        const float* lb = g ? lhb : lzb;
        float ab = 0.0f;
        for (int m = 0; m < DHID; ++m) ab += bg[m] * L[m * DHID + j];
        bfold[nidx] = ab + lb[j];
    }
}

// ----------------------------- weight repacks (f16) ------------------------
// Whh pack: dst[((layer*8+wv)*8+kc)*6+nt][l][e]; wave wv owns h-ch [32wv,32wv+32)
// nt = gate*2+half: ch = gate*256 + wv*32 + half*16 + (l&15); k = kc*32+(l>>4)*8+e
__global__ void pack_whh_kernel(const float* __restrict__ Whh0,
                                const float* __restrict__ Whh1, u16* __restrict__ dst) {
    int id = blockIdx.x * 256 + threadIdx.x;
    if (id >= 2 * 8 * 8 * 6 * 64) return;
    int l = id & 63; int r = id >> 6;
    int nt = r % 6; r /= 6;
    int kc = r % 8; r /= 8;
    int wv = r % 8; r /= 8;
    const float* src = r ? Whh1 : Whh0;
    int ch = (nt >> 1) * 256 + wv * 32 + (nt & 1) * 16 + (l & 15);
    int k0 = kc * 32 + (l >> 4) * 8;
    u16* d = dst + (size_t)id * 8;
    #pragma unroll
    for (int e = 0; e < 8; ++e) d[e] = f2h_bits(src[(size_t)ch * 256 + k0 + e]);
}

// Wih pack: dst[((pb*KC+kc)*6+nt)*64+l][e]; producer pb owns NT [6pb,6pb+6)
__global__ void pack_wih_kernel(const float* __restrict__ W, int K, int KC,
                                u16* __restrict__ dst) {
    int id = blockIdx.x * 256 + threadIdx.x;
    if (id >= 8 * KC * 6 * 64) return;
    int l = id & 63; int r = id >> 6;
    int nt = r % 6; r /= 6;
    int kc = r % KC; r /= KC;
    int pb = r;
    int ch = (pb * 6 + nt) * 16 + (l & 15);
    int k0 = kc * 32 + (l >> 4) * 8;
    u16* d = dst + (size_t)id * 8;
    #pragma unroll
    for (int e = 0; e < 8; ++e) d[e] = f2h_bits(W[(size_t)ch * K + k0 + e]);
}

// --------------- fused TGCN: aggregate + GEMM + cell + l1-dot --------------
__global__ __launch_bounds__(256)
void tgcn_kernel(const float* __restrict__ x, const int* __restrict__ rowptr,
                 const int* __restrict__ col, const float* __restrict__ val,
                 const u16* __restrict__ Wf, const float* __restrict__ bfold,
                 const float* __restrict__ l1W, float* __restrict__ hdot) {
    __shared__ u16 As[64][136];
    const int tid = threadIdx.x;
    const int bx = blockIdx.x;
    const int b = bx >> 3;
    const int n0 = (bx & 7) * 64;
    {
        const int c = tid & 127;
        const int half = tid >> 7;
        for (int it = 0; it < 32; ++it) {
            int r = it * 2 + half;
            int n = n0 + r;
            int s = rowptr[n], e = rowptr[n + 1];
            float acc = 0.0f;
            for (int i = s; i < e; ++i)
                acc += val[i] * x[((size_t)b * NNODE + col[i]) * DCIN + c];
            As[r][c] = f2b(acc);
        }
    }
    __syncthreads();
    const int w = tid >> 6, l = tid & 63;
    const int ncol = l & 15, q = l >> 4, ko = q * 8;
    s8v af[4];
    #pragma unroll
    for (int kc = 0; kc < 4; ++kc)
        af[kc] = *(const s8v*)(&As[w * 16 + ncol][kc * 32 + ko]);
    float partial[4] = {0.f, 0.f, 0.f, 0.f};
    for (int nc = 0; nc < 32; ++nc) {
        int n = nc * 16 + ncol;
        const u16* brow = Wf + (size_t)n * DCIN + ko;
        f4v acc = {0.f, 0.f, 0.f, 0.f};
        #pragma unroll
        for (int kc = 0; kc < 4; ++kc)
            acc = mfma16(af[kc], *(const s8v*)(brow + kc * 32), acc);
        float bias = bfold[n];
        float l1w = l1W[n >> 1];
        #pragma unroll
        for (int rr = 0; rr < 4; ++rr) {
            float v = acc[rr] + bias;
            float o = __shfl_xor(v, 1);
            float zpre = (ncol & 1) ? o : v;
            float hpre = (ncol & 1) ? v : o;
            float hn = (1.0f - sigm(zpre)) * tanh_(hpre);
            hn = hn > 0.0f ? hn : 0.0f;
            if (!(ncol & 1)) partial[rr] += hn * l1w;
        }
    }
    #pragma unroll
    for (int rr = 0; rr < 4; ++rr) {
        float p = partial[rr];
        p += __shfl_xor(p, 1); p += __shfl_xor(p, 2);
        p += __shfl_xor(p, 4); p += __shfl_xor(p, 8);
        if (ncol == 0)
            hdot[bx * 64 + w * 16 + q * 4 + rr] = p;
    }
}

// --------------------- GRU: persistent 18-block pipeline -------------------
// bid 0 = L0, bid 1 = L1, bid 2..9 = feeders (GI0 from x),
// bid 10..17 = helpers (GI1 from h0seq).
// syncb ints: [0] prog0, [1] prog1, [64..127] progH[hb*8+wv],
//             [128..639] stH[slot][wv], [640..1151] stG0[slot][pb],
//             [1152..1663] stG1[slot][pb].  All stamp values = t (init -1).
__global__ __launch_bounds__(512, 1)
void gru_kernel(const float* __restrict__ x,
                const u16* __restrict__ Wpkh, const u16* __restrict__ Wpk0g,
                const u16* __restrict__ Wpk1g,
                const float* __restrict__ bih0, const float* __restrict__ bhh0,
                const float* __restrict__ bih1, const float* __restrict__ bhh1,
                const float* __restrict__ l2W,
                u16* __restrict__ h0seq, float* __restrict__ gi0,
                float* __restrict__ gi1, int* syncb, float* __restrict__ gpart) {
    __shared__ u16 hstage[2][64][256];          // 64KB f16 h ping-pong (L-blocks)
    const int tid = threadIdx.x;
    const int wv = tid >> 6, l = tid & 63;
    const int bid = blockIdx.x;

    int* prog0p = syncb;
    int* prog1p = syncb + 1;
    int* progHp = syncb + 64;
    int* stHp   = syncb + 128;
    int* stG0   = syncb + 640;
    int* stG1   = syncb + 1152;
    char* h0c   = (char*)h0seq;

    if (bid >= 2) {
        // ======================= producers =======================
        const bool isF = bid < 10;
        const int pb = isF ? (bid - 2) : (bid - 10);
        const int mt = wv >> 1, g = wv & 1;     // wave -> (M-tile, NT-half)
        const int KC = isF ? 4 : 8;
        h8v wrp[8][3];
        {
            const u16* base = isF ? Wpk0g : Wpk1g;
            #pragma unroll
            for (int kc = 0; kc < 8; ++kc)
                if (kc < KC) {
                    #pragma unroll
                    for (int j = 0; j < 3; ++j)
                        wrp[kc][j] = *(const h8v*)(base +
                            (((size_t)(pb * KC + kc) * 6) + g * 3 + j) * 512 + l * 8);
                }
        }
        float biasp[3];
        const float* bi_ = isF ? bih0 : bih1;
        const float* bh_ = isF ? bhh0 : bhh1;
        #pragma unroll
        for (int j = 0; j < 3; ++j) {
            int NT = pb * 6 + g * 3 + j;
            int gch = NT * 16 + (l & 15);
            biasp[j] = bi_[gch] + (NT < 32 ? bh_[gch] : 0.0f);  // n-gate: bih only
        }
        int* myprog = isF ? prog0p : prog1p;
        int* mySt   = isF ? stG0 : stG1;
        float* gid  = isF ? gi0 : gi1;

        for (int t = 0; t < NNODE; ++t) {
            int s = t & (RSLOT - 1);
            // ring-overwrite throttle on consumer progress
            while (AT_LD(myprog) < t - SLACK) __builtin_amdgcn_s_sleep(4);
            h8v A[8];
            if (isF) {
                const float* xp = x + ((size_t)(mt * 16 + (l & 15)) * NNODE + t) * DCIN
                                    + (l >> 4) * 8;
                #pragma unroll
                for (int kc = 0; kc < 4; ++kc) {
                    f4v lo = *(const f4v*)(xp + kc * 32);
                    f4v hi = *(const f4v*)(xp + kc * 32 + 4);
                    h8v a;
                    #pragma unroll
                    for (int e = 0; e < 4; ++e) {
                        a[e] = (_Float16)lo[e]; a[4 + e] = (_Float16)hi[e];
                    }
                    A[kc] = a;
                }
            } else {
                int sv = (l < 8) ? AT_LD(stHp + s * 8 + l) : 0x7fffffff;
                while (!__all(sv >= t)) {
                    __builtin_amdgcn_s_sleep(1);
                    if (l < 8) sv = AT_LD(stHp + s * 8 + l);
                }
                #pragma unroll
                for (int kc = 0; kc < 8; ++kc)
                    A[kc] = ld_ring_h8((const u64*)(h0c +
                        (((size_t)(s * 8 + kc) * 4 + mt) * 64 + l) * 16));
            }
            #pragma unroll
            for (int j = 0; j < 3; ++j) {
                f4v acc = {biasp[j], biasp[j], biasp[j], biasp[j]};
                #pragma unroll
                for (int kc = 0; kc < 8; ++kc)
                    if (kc < KC) acc = mfma16h(A[kc], wrp[kc][j], acc);
                int NT = pb * 6 + g * 3 + j;
                st_ring_f4((u64*)((char*)gid +
                    (((size_t)s * 48 + NT) * 4 + mt) * 1024 + l * 16), acc);
            }
            if (!isF && l == 0) AT_ST(progHp + pb * 8 + wv, t);   // consumed h0(t)
            asm volatile("s_waitcnt vmcnt(0)" ::: "memory");
            __syncthreads();
            if (tid == 0) AT_ST(mySt + s * 8 + pb, t);            // slot complete
        }
        return;
    }

    // ========================= L-blocks (recurrent) =========================
    const bool isL1 = (bid == 1);
    h8v wr[8][6];                                // full Whh slice in VGPRs
    #pragma unroll
    for (int kc = 0; kc < 8; ++kc)
        #pragma unroll
        for (int nt = 0; nt < 6; ++nt)
            wr[kc][nt] = *(const h8v*)(Wpkh +
                ((((size_t)(isL1 ? 8 : 0) + wv) * 8 + kc) * 6 + nt) * 512 + l * 8);
    const float* bhh_ = isL1 ? bhh1 : bhh0;
    float bhn[2], l2v[2];
    #pragma unroll
    for (int h = 0; h < 2; ++h) {
        int ch = wv * 32 + h * 16 + (l & 15);
        bhn[h] = bhh_[512 + ch];
        l2v[h] = isL1 ? l2W[ch] : 0.0f;
    }
    const char* gis = (const char*)(isL1 ? gi1 : gi0);
    int* stG = isL1 ? stG1 : stG0;
    char* hst = (char*)&hstage[0][0][0];

    int stv = (l < 8) ? AT_LD(stG + l) : 0x7fffffff;       // stamps for t=0
    int phv = 0x7fffffff;
    if (!isL1) phv = AT_LD(progHp + l);                     // l<64 always
    f4v gcur[6];
    __syncthreads();

    for (int t = 0; t < NNODE; ++t) {
        const int s = t & (RSLOT - 1);
        const int rb = t & 1, wb = rb ^ 1;
        // GI(t) stamp check (stv prefetched mid previous step)
        while (!__all(stv >= t)) {
            __builtin_amdgcn_s_sleep(1);
            if (l < 8) stv = AT_LD(stG + s * 8 + l);
        }
        if (!isL1) {
            // h0seq(t-1) stamp: all publishes drained (vmem idle here -> cheap)
            if (t > 0) {
                asm volatile("s_waitcnt vmcnt(0)" ::: "memory");
                if (l == 0) AT_ST(stHp + ((t - 1) & (RSLOT - 1)) * 8 + wv, t - 1);
            }
            // ring-overwrite throttle: helpers must be past t-64
            while (!__all(phv >= t - SLACK)) {
                __builtin_amdgcn_s_sleep(1);
                phv = AT_LD(progHp + l);
            }
        }
        // GI loads for mt0 (consumed at its epilogue, ~full MFMA phase later)
        #pragma unroll
        for (int j = 0; j < 6; ++j) {
            int NT = (j >> 1) * 16 + 2 * wv + (j & 1);
            gcur[j] = ld_ring_f4((const u64*)(gis +
                (((size_t)s * 48 + NT) * 4 + 0) * 1024 + l * 16));
        }
        #pragma unroll
        for (int mt = 0; mt < 4; ++mt) {
            // mid-step prefetches (off critical path)
            if (mt == 1 && l < 8 && t + 1 < NNODE)
                stv = AT_LD(stG + ((t + 1) & (RSLOT - 1)) * 8 + l);
            if (mt == 2 && !isL1)
                phv = AT_LD(progHp + l);
            // ---- gh = h(t-1) @ Whh^T for this M-tile ----
            f4v acc[6];
            #pragma unroll
            for (int nt = 0; nt < 6; ++nt) acc[nt] = (f4v){0.f, 0.f, 0.f, 0.f};
            if (t > 0) {
                #pragma unroll
                for (int kc = 0; kc < 8; ++kc) {
                    int b = mt * 16 + (l & 15);
                    int boff = (b << 9) + ((((kc << 6) + ((l >> 4) << 4)) ^ ((b & 7) << 4)));
                    h8v A = *(const h8v*)(hst + rb * 32768 + boff);
                    #pragma unroll
                    for (int nt = 0; nt < 6; ++nt)
                        acc[nt] = mfma16h(A, wr[kc][nt], acc[nt]);
                }
            }
            // ---- gate epilogue ----
            float pd01[4];
            #pragma unroll
            for (int rr = 0; rr < 4; ++rr) {
                int b2 = mt * 16 + (l >> 4) * 4 + rr;
                float pdv = 0.f;
                #pragma unroll
                for (int h = 0; h < 2; ++h) {
                    float rv = sigm(acc[h][rr] + gcur[h][rr]);
                    float zv = sigm(acc[2 + h][rr] + gcur[2 + h][rr]);
                    float nv = tanh_(gcur[4 + h][rr] + rv * (acc[4 + h][rr] + bhn[h]));
                    int ch2 = (wv * 32 + h * 16 + (l & 15)) * 2;
                    int boff = (b2 << 9) + (ch2 ^ ((b2 & 7) << 4));
                    float ho = 0.f;
                    if (t > 0) {
                        u16 hb_ = *(const u16*)(hst + rb * 32768 + boff);
                        ho = (float)__builtin_bit_cast(_Float16, hb_);
                    }
                    float hn = nv + zv * (ho - nv);
                    *(u16*)(hst + wb * 32768 + boff) = f2h_bits(hn);
                    pdv += hn * l2v[h];
                }
                pd01[rr] = pdv;
            }
            // ---- issue GI loads for mt+1 (gcur consumed above) ----
            if (mt < 3) {
                #pragma unroll
                for (int j = 0; j < 6; ++j) {
                    int NT = (j >> 1) * 16 + 2 * wv + (j & 1);
                    gcur[j] = ld_ring_f4((const u64*)(gis +
                        (((size_t)s * 48 + NT) * 4 + (mt + 1)) * 1024 + l * 16));
                }
            }
            // ---- publish own chunk (L0) / l2-dot partials (L1) ----
            if (!isL1) {
                asm volatile("s_waitcnt lgkmcnt(0)" ::: "memory");
                int b = mt * 16 + (l & 15);
                int boff = (b << 9) + ((((wv << 6) + ((l >> 4) << 4)) ^ ((b & 7) << 4)));
                h8v hv = *(const h8v*)(hst + wb * 32768 + boff);
                st_ring_h8((u64*)(h0c + (((size_t)(s * 8 + wv) * 4 + mt) * 64 + l) * 16), hv);
            } else {
                #pragma unroll
                for (int rr = 0; rr < 4; ++rr) {
                    float v = pd01[rr];
                    v += __shfl_xor(v, 1); v += __shfl_xor(v, 2);
                    v += __shfl_xor(v, 4); v += __shfl_xor(v, 8);
                    pd01[rr] = v;
                }
                if ((l & 15) == 0) {
                    f4v pv = {pd01[0], pd01[1], pd01[2], pd01[3]};
                    *(f4v*)(gpart + ((size_t)t * 8 + wv) * 64 + mt * 16 + (l >> 4) * 4) = pv;
                }
            }
        }
        if (wv == 0 && l == 0) AT_ST(isL1 ? prog1p : prog0p, t);
        __syncthreads();    // h(t) complete in hstage[wb] for all waves
    }
    if (!isL1) {            // flush final h0seq stamp
        asm volatile("s_waitcnt vmcnt(0)" ::: "memory");
        if (l == 0) AT_ST(stHp + ((NNODE - 1) & (RSLOT - 1)) * 8 + wv, NNODE - 1);
    }
}

// ------------------------------- final head --------------------------------
__global__ __launch_bounds__(256)
void head_kernel(const float* __restrict__ gpartg, const float* __restrict__ hdot,
                 const float* __restrict__ l1b, const float* __restrict__ l2b,
                 const float* __restrict__ l3W, const float* __restrict__ l3b,
                 float* __restrict__ out) {
    int idx = blockIdx.x * 256 + threadIdx.x;
    if (idx >= NBATCH * NNODE * 12) return;
    int r = idx / 12, oc = idx - r * 12;
    int b = r >> 9, n = r & 511;
    float g = 0.0f;
    #pragma unroll
    for (int k = 0; k < 8; ++k) g += gpartg[((size_t)n * 8 + k) * 64 + b];
    g += l2b[0];
    float hh = hdot[r] + l1b[0];
    out[idx] = g * l3W[oc] + hh * l3W[12 + oc] + l3b[oc];
}

// ---------------------- static side stream (for capture fork) --------------
static hipStream_t g_side = nullptr;
static hipEvent_t  g_evA  = nullptr;
static hipEvent_t  g_evB  = nullptr;
namespace {
struct SideInit {
    SideInit() {
        if (hipStreamCreateWithFlags(&g_side, hipStreamNonBlocking) != hipSuccess) g_side = nullptr;
        if (hipEventCreateWithFlags(&g_evA, hipEventDisableTiming) != hipSuccess) g_evA = nullptr;
        if (hipEventCreateWithFlags(&g_evB, hipEventDisableTiming) != hipSuccess) g_evB = nullptr;
    }
};
static SideInit g_side_init;
}

// ------------------------------ host launcher ------------------------------
extern "C" void kernel_launch(void* const* d_in, const int* in_sizes, int n_in,
                              void* d_out, int out_size, void* d_ws, size_t ws_size,
                              hipStream_t stream) {
    const float* x    = (const float*)d_in[0];
    const int*   ei   = (const int*)  d_in[1];
    const float* ew   = (const float*)d_in[2];
    const float* Wz   = (const float*)d_in[3];
    const float* bz   = (const float*)d_in[4];
    const float* lzW  = (const float*)d_in[5];
    const float* lzb  = (const float*)d_in[6];
    // d_in[7..10] (TGCN r-gate) unused: H0 == 0
    const float* Wh   = (const float*)d_in[11];
    const float* bh   = (const float*)d_in[12];
    const float* lhW  = (const float*)d_in[13];
    const float* lhb  = (const float*)d_in[14];
    const float* Wih0 = (const float*)d_in[15];
    const float* Whh0 = (const float*)d_in[16];
    const float* bih0 = (const float*)d_in[17];
    const float* bhh0 = (const float*)d_in[18];
    const float* Wih1 = (const float*)d_in[19];
    const float* Whh1 = (const float*)d_in[20];
    const float* bih1 = (const float*)d_in[21];
    const float* bhh1 = (const float*)d_in[22];
    const float* l1W  = (const float*)d_in[23];
    const float* l1b  = (const float*)d_in[24];
    const float* l2W  = (const float*)d_in[25];
    const float* l2b  = (const float*)d_in[26];
    const float* l3W  = (const float*)d_in[27];
    const float* l3b  = (const float*)d_in[28];

    char* ws = (char*)d_ws;
    size_t o = 0;
    auto take = [&](size_t nbytes) {
        char* p = ws + o;
        o = (o + nbytes + 255) & ~(size_t)255;
        return p;
    };
    float* deg    = (float*)take(NNODE * 4);
    float* dinv   = (float*)take(NNODE * 4);
    int*   rowptr = (int*)  take((NNODE + 1) * 4);
    int*   cursor = (int*)  take(NNODE * 4);
    int*   col    = (int*)  take((NEDGE + NNODE) * 4);
    float* val    = (float*)take((NEDGE + NNODE) * 4);
    u16*   Wf     = (u16*)  take((size_t)512 * DCIN * 2);
    float* bfold  = (float*)take(512 * 4);
    float* hdot   = (float*)take((size_t)NBATCH * NNODE * 4);
    float* gpart  = (float*)take((size_t)NNODE * 8 * 64 * 4);            // 1 MB
    u16*   Wpkh   = (u16*)  take((size_t)2 * 8 * 8 * 6 * 64 * 8 * 2);    // 786 KB
    u16*   Wpk0g  = (u16*)  take((size_t)8 * 4 * 6 * 64 * 8 * 2);        // 196 KB
    u16*   Wpk1g  = (u16*)  take((size_t)8 * 8 * 6 * 64 * 8 * 2);        // 393 KB
    u16*   h0seq  = (u16*)  take((size_t)RSLOT * 8 * 4 * 64 * 8 * 2);    // 2 MB
    float* gi0    = (float*)take((size_t)RSLOT * 48 * 4 * 64 * 4 * 4);   // 12.6 MB
    float* gi1    = (float*)take((size_t)RSLOT * 48 * 4 * 64 * 4 * 4);   // 12.6 MB
    int*   syncb  = (int*)  take(8192);
    if (o > ws_size) return;   // clean-failure signature: absmax == 4.57e-2

    const bool fork = (g_side && g_evA && g_evB);
    hipStream_t sideS = fork ? g_side : stream;

    // main: init (deg/counts + stamps/progress to -1)
    init_kernel<<<8, 256, 0, stream>>>(deg, cursor, syncb);

    if (fork) {
        hipEventRecord(g_evA, stream);
        hipStreamWaitEvent(sideS, g_evA, 0);
    }

    // side branch: graph preprocessing -> fold -> TGCN (independent of GRU)
    edge_deg_kernel<<<NEDGE / 256, 256, 0, sideS>>>(ei, ew, deg, cursor);
    scan_kernel<<<1, NNODE, 0, sideS>>>(deg, cursor, dinv, rowptr, cursor, col, val);
    fill_kernel<<<NEDGE / 256, 256, 0, sideS>>>(ei, ew, dinv, cursor, col, val);
    fold_kernel<<<512, DCIN, 0, sideS>>>(Wz, lzW, bz, lzb, Wh, lhW, bh, lhb, Wf, bfold);
    tgcn_kernel<<<512, 256, 0, sideS>>>(x, rowptr, col, val, Wf, bfold, l1W, hdot);
    if (fork) hipEventRecord(g_evB, sideS);

    // main branch: weight repacks -> persistent GRU pipeline
    pack_whh_kernel<<<(2 * 8 * 8 * 6 * 64 + 255) / 256, 256, 0, stream>>>(Whh0, Whh1, Wpkh);
    pack_wih_kernel<<<(8 * 4 * 6 * 64 + 255) / 256, 256, 0, stream>>>(Wih0, DCIN, 4, Wpk0g);
    pack_wih_kernel<<<(8 * 8 * 6 * 64 + 255) / 256, 256, 0, stream>>>(Wih1, DHID, 8, Wpk1g);
    gru_kernel<<<18, 512, 0, stream>>>(x, Wpkh, Wpk0g, Wpk1g, bih0, bhh0,
                                       bih1, bhh1, l2W, h0seq, gi0, gi1,
                                       syncb, gpart);

    // join + head
    if (fork) hipStreamWaitEvent(stream, g_evB, 0);
    head_kernel<<<(NBATCH * NNODE * 12 + 255) / 256, 256, 0, stream>>>(
        gpart, hdot, l1b, l2b, l3W, l3b, (float*)d_out);
    (void)in_sizes; (void)n_in; (void)out_size;
}

// Round 4
// 9483.850 us; speedup vs baseline: 1.3666x; 1.3666x over previous
//
#include <hip/hip_runtime.h>

// ---------------------------------------------------------------------------
// TGCN2 forward, MI355X gfx950. R14 = R13 (intra-block recurrence) + spill fix.
// R13 post-mortem: allocator capped at 128 VGPRs and spilled wr[8][6] (192
// regs) to scratch -> WRITE_SIZE 70->429MB, 25us/step. Fixes:
//   (1) amdgpu_waves_per_eu(2,2): pin 2 waves/EU -> 256-VGPR budget, no
//       occupancy-driven spilling.
//   (2) kc=7 Whh chunk moved to LDS (whhlds 48KB; wr 192->168 regs).
//   (3) #pragma unroll 1 on the mt loop: one M-tile body live at a time
//       (full unroll let the scheduler interleave 4 bodies -> pressure blowup).
// Structure (validated correct in R13, absmax 2.44e-4):
//   - L0, L1 = ONE block each (8 waves); h ping-pong in LDS (64KB), per-step
//     exchange intra-CU. Whh f16 in VGPRs+LDS.
//   - 8 feeder blocks stream GI0 = x@Wih0^T+b; 8 helper blocks stream
//     GI1 = h0seq@Wih1^T+b. 64-slot rings, monotonic stamps, SLACK=56.
// TGCN branch unchanged, on side stream (R7).
// ---------------------------------------------------------------------------

typedef unsigned short u16;
typedef unsigned long long u64;
typedef short s8v __attribute__((ext_vector_type(8)));
typedef _Float16 h8v __attribute__((ext_vector_type(8)));
typedef float f4v __attribute__((ext_vector_type(4)));

#define NBATCH 64
#define NNODE  512
#define DCIN   128
#define DHID   256
#define NEDGE  8192
#define RSLOT  64
#define SLACK  56

#define AT_LD(p)   __hip_atomic_load((p), __ATOMIC_RELAXED, __HIP_MEMORY_SCOPE_AGENT)
#define AT_ST(p,v) __hip_atomic_store((p), (v), __ATOMIC_RELAXED, __HIP_MEMORY_SCOPE_AGENT)

__device__ __forceinline__ u16 f2b(float f) {
    union { float f; unsigned int i; } v; v.f = f;
    unsigned int x = v.i;
    return (u16)((x + 0x7FFFu + ((x >> 16) & 1u)) >> 16);   // RNE (TGCN path)
}
__device__ __forceinline__ float sigm(float x)  { return 1.0f / (1.0f + __expf(-x)); }
__device__ __forceinline__ float tanh_(float x) { return 1.0f - 2.0f / (1.0f + __expf(2.0f * x)); }
__device__ __forceinline__ f4v mfma16(s8v a, s8v b, f4v c) {
    return __builtin_amdgcn_mfma_f32_16x16x32_bf16(a, b, c, 0, 0, 0);
}
__device__ __forceinline__ f4v mfma16h(h8v a, h8v b, f4v c) {
    return __builtin_amdgcn_mfma_f32_16x16x32_f16(a, b, c, 0, 0, 0);
}
__device__ __forceinline__ f4v ld_ring_f4(const u64* p) {
    union { u64 d[2]; f4v v; } u;
    u.d[0] = AT_LD(p); u.d[1] = AT_LD(p + 1);
    return u.v;
}
__device__ __forceinline__ void st_ring_f4(u64* p, f4v v) {
    union { f4v v; u64 d[2]; } u; u.v = v;
    AT_ST(p, u.d[0]); AT_ST(p + 1, u.d[1]);
}
__device__ __forceinline__ h8v ld_ring_h8(const u64* p) {
    union { u64 d[2]; h8v v; } u;
    u.d[0] = AT_LD(p); u.d[1] = AT_LD(p + 1);
    return u.v;
}
__device__ __forceinline__ void st_ring_h8(u64* p, h8v v) {
    union { h8v v; u64 d[2]; } u; u.v = v;
    AT_ST(p, u.d[0]); AT_ST(p + 1, u.d[1]);
}
__device__ __forceinline__ u16 f2h_bits(float f) {
    _Float16 h = (_Float16)f;
    return __builtin_bit_cast(u16, h);
}

// --------------------------- graph preprocessing ---------------------------
__global__ void init_kernel(float* deg, int* counts, int* syncb) {
    int i = blockIdx.x * blockDim.x + threadIdx.x;
    if (i < NNODE) { deg[i] = 2.0f; counts[i] = 1; }
    if (i < 2048) syncb[i] = -1;   // prog/progH/stamps: must be < 0
}

__global__ void edge_deg_kernel(const int* __restrict__ ei, const float* __restrict__ ew,
                                float* deg, int* counts) {
    int e = blockIdx.x * blockDim.x + threadIdx.x;
    if (e < NEDGE) {
        int t = ei[NEDGE + e];
        atomicAdd(&deg[t], ew[e]);
        atomicAdd(&counts[t], 1);
    }
}

__global__ void scan_kernel(const float* __restrict__ deg, const int* __restrict__ counts,
                            float* __restrict__ dinv, int* __restrict__ rowptr,
                            int* __restrict__ cursor, int* __restrict__ col,
                            float* __restrict__ val) {
    __shared__ int sc[NNODE];
    int i = threadIdx.x;
    float d = deg[i];
    float di = (d > 0.0f) ? (1.0f / sqrtf(d)) : 0.0f;
    dinv[i] = di;
    int cnt = counts[i];
    sc[i] = cnt;
    __syncthreads();
    for (int ofs = 1; ofs < NNODE; ofs <<= 1) {
        int add = (i >= ofs) ? sc[i - ofs] : 0;
        __syncthreads();
        sc[i] += add;
        __syncthreads();
    }
    int ex = sc[i] - cnt;
    rowptr[i] = ex;
    if (i == NNODE - 1) rowptr[NNODE] = sc[NNODE - 1];
    col[ex] = i;
    val[ex] = di * 2.0f * di;
    cursor[i] = ex + 1;
}

__global__ void fill_kernel(const int* __restrict__ ei, const float* __restrict__ ew,
                            const float* __restrict__ dinv, int* cursor,
                            int* __restrict__ col, float* __restrict__ val) {
    int e = blockIdx.x * blockDim.x + threadIdx.x;
    if (e < NEDGE) {
        int s = ei[e], t = ei[NEDGE + e];
        int p = atomicAdd(&cursor[t], 1);
        col[p] = s;
        val[p] = dinv[s] * ew[e] * dinv[t];
    }
}

// Wf[2j+g][k] = sum_m Wg[k][m]*Lg_top[m][j]; bfold[2j+g] = bg@Lg_top[:,j]+lgb[j]
__global__ void fold_kernel(const float* __restrict__ Wz, const float* __restrict__ lzW,
                            const float* __restrict__ bz, const float* __restrict__ lzb,
                            const float* __restrict__ Wh, const float* __restrict__ lhW,
                            const float* __restrict__ bh, const float* __restrict__ lhb,
                            u16* __restrict__ Wf, float* __restrict__ bfold) {
    int nidx = blockIdx.x;
    int g = nidx & 1, j = nidx >> 1;
    int k = threadIdx.x;
    const float* W = g ? Wh : Wz;
    const float* L = g ? lhW : lzW;
    float acc = 0.0f;
    for (int m = 0; m < DHID; ++m)
        acc += W[k * DHID + m] * L[m * DHID + j];
    Wf[nidx * DCIN + k] = f2b(acc);
    if (k == 0) {
        const float* bg = g ? bh : bz;
        const float* lb = g ? lhb : lzb;
        float ab = 0.0f;
        for (int m = 0; m < DHID; ++m) ab += bg[m] * L[m * DHID + j];
        bfold[nidx] = ab + lb[j];
    }
}

// ----------------------------- weight repacks (f16) ------------------------
// Whh pack: dst[((layer*8+wv)*8+kc)*6+nt][l][e]; wave wv owns h-ch [32wv,32wv+32)
// nt = gate*2+half: ch = gate*256 + wv*32 + half*16 + (l&15); k = kc*32+(l>>4)*8+e
__global__ void pack_whh_kernel(const float* __restrict__ Whh0,
                                const float* __restrict__ Whh1, u16* __restrict__ dst) {
    int id = blockIdx.x * 256 + threadIdx.x;
    if (id >= 2 * 8 * 8 * 6 * 64) return;
    int l = id & 63; int r = id >> 6;
    int nt = r % 6; r /= 6;
    int kc = r % 8; r /= 8;
    int wv = r % 8; r /= 8;
    const float* src = r ? Whh1 : Whh0;
    int ch = (nt >> 1) * 256 + wv * 32 + (nt & 1) * 16 + (l & 15);
    int k0 = kc * 32 + (l >> 4) * 8;
    u16* d = dst + (size_t)id * 8;
    #pragma unroll
    for (int e = 0; e < 8; ++e) d[e] = f2h_bits(src[(size_t)ch * 256 + k0 + e]);
}

// Wih pack: dst[((pb*KC+kc)*6+nt)*64+l][e]; producer pb owns NT [6pb,6pb+6)
__global__ void pack_wih_kernel(const float* __restrict__ W, int K, int KC,
                                u16* __restrict__ dst) {
    int id = blockIdx.x * 256 + threadIdx.x;
    if (id >= 8 * KC * 6 * 64) return;
    int l = id & 63; int r = id >> 6;
    int nt = r % 6; r /= 6;
    int kc = r % KC; r /= KC;
    int pb = r;
    int ch = (pb * 6 + nt) * 16 + (l & 15);
    int k0 = kc * 32 + (l >> 4) * 8;
    u16* d = dst + (size_t)id * 8;
    #pragma unroll
    for (int e = 0; e < 8; ++e) d[e] = f2h_bits(W[(size_t)ch * K + k0 + e]);
}

// --------------- fused TGCN: aggregate + GEMM + cell + l1-dot --------------
__global__ __launch_bounds__(256)
void tgcn_kernel(const float* __restrict__ x, const int* __restrict__ rowptr,
                 const int* __restrict__ col, const float* __restrict__ val,
                 const u16* __restrict__ Wf, const float* __restrict__ bfold,
                 const float* __restrict__ l1W, float* __restrict__ hdot) {
    __shared__ u16 As[64][136];
    const int tid = threadIdx.x;
    const int bx = blockIdx.x;
    const int b = bx >> 3;
    const int n0 = (bx & 7) * 64;
    {
        const int c = tid & 127;
        const int half = tid >> 7;
        for (int it = 0; it < 32; ++it) {
            int r = it * 2 + half;
            int n = n0 + r;
            int s = rowptr[n], e = rowptr[n + 1];
            float acc = 0.0f;
            for (int i = s; i < e; ++i)
                acc += val[i] * x[((size_t)b * NNODE + col[i]) * DCIN + c];
            As[r][c] = f2b(acc);
        }
    }
    __syncthreads();
    const int w = tid >> 6, l = tid & 63;
    const int ncol = l & 15, q = l >> 4, ko = q * 8;
    s8v af[4];
    #pragma unroll
    for (int kc = 0; kc < 4; ++kc)
        af[kc] = *(const s8v*)(&As[w * 16 + ncol][kc * 32 + ko]);
    float partial[4] = {0.f, 0.f, 0.f, 0.f};
    for (int nc = 0; nc < 32; ++nc) {
        int n = nc * 16 + ncol;
        const u16* brow = Wf + (size_t)n * DCIN + ko;
        f4v acc = {0.f, 0.f, 0.f, 0.f};
        #pragma unroll
        for (int kc = 0; kc < 4; ++kc)
            acc = mfma16(af[kc], *(const s8v*)(brow + kc * 32), acc);
        float bias = bfold[n];
        float l1w = l1W[n >> 1];
        #pragma unroll
        for (int rr = 0; rr < 4; ++rr) {
            float v = acc[rr] + bias;
            float o = __shfl_xor(v, 1);
            float zpre = (ncol & 1) ? o : v;
            float hpre = (ncol & 1) ? v : o;
            float hn = (1.0f - sigm(zpre)) * tanh_(hpre);
            hn = hn > 0.0f ? hn : 0.0f;
            if (!(ncol & 1)) partial[rr] += hn * l1w;
        }
    }
    #pragma unroll
    for (int rr = 0; rr < 4; ++rr) {
        float p = partial[rr];
        p += __shfl_xor(p, 1); p += __shfl_xor(p, 2);
        p += __shfl_xor(p, 4); p += __shfl_xor(p, 8);
        if (ncol == 0)
            hdot[bx * 64 + w * 16 + q * 4 + rr] = p;
    }
}

// --------------------- GRU: persistent 18-block pipeline -------------------
// bid 0 = L0, bid 1 = L1, bid 2..9 = feeders (GI0 from x),
// bid 10..17 = helpers (GI1 from h0seq).
// syncb ints: [0] prog0, [1] prog1, [64..127] progH[hb*8+wv],
//             [128..639] stH[slot][wv], [640..1151] stG0[slot][pb],
//             [1152..1663] stG1[slot][pb].  All stamp values = t (init -1).
__global__ __launch_bounds__(512)
__attribute__((amdgpu_waves_per_eu(2, 2)))
void gru_kernel(const float* __restrict__ x,
                const u16* __restrict__ Wpkh, const u16* __restrict__ Wpk0g,
                const u16* __restrict__ Wpk1g,
                const float* __restrict__ bih0, const float* __restrict__ bhh0,
                const float* __restrict__ bih1, const float* __restrict__ bhh1,
                const float* __restrict__ l2W,
                u16* __restrict__ h0seq, float* __restrict__ gi0,
                float* __restrict__ gi1, int* syncb, float* __restrict__ gpart) {
    __shared__ u16 hstage[2][64][256];          // 64KB f16 h ping-pong (L-blocks)
    __shared__ u16 whhlds[8][6][512];           // 48KB: kc=7 Whh chunk per wave

    const int tid = threadIdx.x;
    const int wv = tid >> 6, l = tid & 63;
    const int bid = blockIdx.x;

    int* prog0p = syncb;
    int* prog1p = syncb + 1;
    int* progHp = syncb + 64;
    int* stHp   = syncb + 128;
    int* stG0   = syncb + 640;
    int* stG1   = syncb + 1152;
    char* h0c   = (char*)h0seq;

    if (bid >= 2) {
        // ======================= producers =======================
        const bool isF = bid < 10;
        const int pb = isF ? (bid - 2) : (bid - 10);
        const int mt = wv >> 1, g = wv & 1;     // wave -> (M-tile, NT-half)
        const int KC = isF ? 4 : 8;
        h8v wrp[8][3];
        {
            const u16* base = isF ? Wpk0g : Wpk1g;
            #pragma unroll
            for (int kc = 0; kc < 8; ++kc)
                if (kc < KC) {
                    #pragma unroll
                    for (int j = 0; j < 3; ++j)
                        wrp[kc][j] = *(const h8v*)(base +
                            (((size_t)(pb * KC + kc) * 6) + g * 3 + j) * 512 + l * 8);
                }
        }
        float biasp[3];
        const float* bi_ = isF ? bih0 : bih1;
        const float* bh_ = isF ? bhh0 : bhh1;
        #pragma unroll
        for (int j = 0; j < 3; ++j) {
            int NT = pb * 6 + g * 3 + j;
            int gch = NT * 16 + (l & 15);
            biasp[j] = bi_[gch] + (NT < 32 ? bh_[gch] : 0.0f);  // n-gate: bih only
        }
        int* myprog = isF ? prog0p : prog1p;
        int* mySt   = isF ? stG0 : stG1;
        float* gid  = isF ? gi0 : gi1;

        for (int t = 0; t < NNODE; ++t) {
            int s = t & (RSLOT - 1);
            // ring-overwrite throttle on consumer progress
            while (AT_LD(myprog) < t - SLACK) __builtin_amdgcn_s_sleep(4);
            h8v A[8];
            if (isF) {
                const float* xp = x + ((size_t)(mt * 16 + (l & 15)) * NNODE + t) * DCIN
                                    + (l >> 4) * 8;
                #pragma unroll
                for (int kc = 0; kc < 4; ++kc) {
                    f4v lo = *(const f4v*)(xp + kc * 32);
                    f4v hi = *(const f4v*)(xp + kc * 32 + 4);
                    h8v a;
                    #pragma unroll
                    for (int e = 0; e < 4; ++e) {
                        a[e] = (_Float16)lo[e]; a[4 + e] = (_Float16)hi[e];
                    }
                    A[kc] = a;
                }
            } else {
                int sv = (l < 8) ? AT_LD(stHp + s * 8 + l) : 0x7fffffff;
                while (!__all(sv >= t)) {
                    __builtin_amdgcn_s_sleep(1);
                    if (l < 8) sv = AT_LD(stHp + s * 8 + l);
                }
                #pragma unroll
                for (int kc = 0; kc < 8; ++kc)
                    A[kc] = ld_ring_h8((const u64*)(h0c +
                        (((size_t)(s * 8 + kc) * 4 + mt) * 64 + l) * 16));
            }
            #pragma unroll
            for (int j = 0; j < 3; ++j) {
                f4v acc = {biasp[j], biasp[j], biasp[j], biasp[j]};
                #pragma unroll
                for (int kc = 0; kc < 8; ++kc)
                    if (kc < KC) acc = mfma16h(A[kc], wrp[kc][j], acc);
                int NT = pb * 6 + g * 3 + j;
                st_ring_f4((u64*)((char*)gid +
                    (((size_t)s * 48 + NT) * 4 + mt) * 1024 + l * 16), acc);
            }
            if (!isF && l == 0) AT_ST(progHp + pb * 8 + wv, t);   // consumed h0(t)
            asm volatile("s_waitcnt vmcnt(0)" ::: "memory");
            __syncthreads();
            if (tid == 0) AT_ST(mySt + s * 8 + pb, t);            // slot complete
        }
        return;
    }

    // ========================= L-blocks (recurrent) =========================
    const bool isL1 = (bid == 1);
    h8v wr[7][6];                                // Whh kc 0..6 in VGPRs (168)
    #pragma unroll
    for (int kc = 0; kc < 7; ++kc)
        #pragma unroll
        for (int nt = 0; nt < 6; ++nt)
            wr[kc][nt] = *(const h8v*)(Wpkh +
                ((((size_t)(isL1 ? 8 : 0) + wv) * 8 + kc) * 6 + nt) * 512 + l * 8);
    // kc = 7 chunk -> LDS (per-wave slice)
    #pragma unroll
    for (int nt = 0; nt < 6; ++nt)
        *(h8v*)&whhlds[wv][nt][l * 8] = *(const h8v*)(Wpkh +
            ((((size_t)(isL1 ? 8 : 0) + wv) * 8 + 7) * 6 + nt) * 512 + l * 8);
    const float* bhh_ = isL1 ? bhh1 : bhh0;
    float bhn[2], l2v[2];
    #pragma unroll
    for (int h = 0; h < 2; ++h) {
        int ch = wv * 32 + h * 16 + (l & 15);
        bhn[h] = bhh_[512 + ch];
        l2v[h] = isL1 ? l2W[ch] : 0.0f;
    }
    const char* gis = (const char*)(isL1 ? gi1 : gi0);
    int* stG = isL1 ? stG1 : stG0;
    char* hst = (char*)&hstage[0][0][0];

    int stv = (l < 8) ? AT_LD(stG + l) : 0x7fffffff;       // stamps for t=0
    int phv = 0x7fffffff;
    if (!isL1) phv = AT_LD(progHp + l);                     // l<64 always
    f4v gcur[6];
    __syncthreads();

    for (int t = 0; t < NNODE; ++t) {
        const int s = t & (RSLOT - 1);
        const int rb = t & 1, wb = rb ^ 1;
        // GI(t) stamp check (stv prefetched mid previous step)
        while (!__all(stv >= t)) {
            __builtin_amdgcn_s_sleep(1);
            if (l < 8) stv = AT_LD(stG + s * 8 + l);
        }
        if (!isL1) {
            // h0seq(t-1) stamp: all publishes drained (vmem idle here -> cheap)
            if (t > 0) {
                asm volatile("s_waitcnt vmcnt(0)" ::: "memory");
                if (l == 0) AT_ST(stHp + ((t - 1) & (RSLOT - 1)) * 8 + wv, t - 1);
            }
            // ring-overwrite throttle: helpers must be past t-64
            while (!__all(phv >= t - SLACK)) {
                __builtin_amdgcn_s_sleep(1);
                phv = AT_LD(progHp + l);
            }
        }
        // GI loads for mt0 (consumed at its epilogue, ~full MFMA phase later)
        #pragma unroll
        for (int j = 0; j < 6; ++j) {
            int NT = (j >> 1) * 16 + 2 * wv + (j & 1);
            gcur[j] = ld_ring_f4((const u64*)(gis +
                (((size_t)s * 48 + NT) * 4 + 0) * 1024 + l * 16));
        }
        #pragma unroll 1
        for (int mt = 0; mt < 4; ++mt) {
            // mid-step prefetches (off critical path)
            if (mt == 1 && l < 8 && t + 1 < NNODE)
                stv = AT_LD(stG + ((t + 1) & (RSLOT - 1)) * 8 + l);
            if (mt == 2 && !isL1)
                phv = AT_LD(progHp + l);
            // ---- gh = h(t-1) @ Whh^T for this M-tile ----
            f4v acc[6];
            #pragma unroll
            for (int nt = 0; nt < 6; ++nt) acc[nt] = (f4v){0.f, 0.f, 0.f, 0.f};
            if (t > 0) {
                const int b = mt * 16 + (l & 15);
                #pragma unroll
                for (int kc = 0; kc < 7; ++kc) {
                    int boff = (b << 9) + ((((kc << 6) + ((l >> 4) << 4)) ^ ((b & 7) << 4)));
                    h8v A = *(const h8v*)(hst + rb * 32768 + boff);
                    #pragma unroll
                    for (int nt = 0; nt < 6; ++nt)
                        acc[nt] = mfma16h(A, wr[kc][nt], acc[nt]);
                }
                {   // kc = 7 from LDS (brief lives)
                    int boff = (b << 9) + ((((7 << 6) + ((l >> 4) << 4)) ^ ((b & 7) << 4)));
                    h8v A = *(const h8v*)(hst + rb * 32768 + boff);
                    #pragma unroll
                    for (int nt = 0; nt < 6; ++nt) {
                        h8v wb7 = *(const h8v*)&whhlds[wv][nt][l * 8];
                        acc[nt] = mfma16h(A, wb7, acc[nt]);
                    }
                }
            }
            // ---- gate epilogue ----
            float pd01[4];
            #pragma unroll
            for (int rr = 0; rr < 4; ++rr) {
                int b2 = mt * 16 + (l >> 4) * 4 + rr;
                float pdv = 0.f;
                #pragma unroll
                for (int h = 0; h < 2; ++h) {
                    float rv = sigm(acc[h][rr] + gcur[h][rr]);
                    float zv = sigm(acc[2 + h][rr] + gcur[2 + h][rr]);
                    float nv = tanh_(gcur[4 + h][rr] + rv * (acc[4 + h][rr] + bhn[h]));
                    int ch2 = (wv * 32 + h * 16 + (l & 15)) * 2;
                    int boff = (b2 << 9) + (ch2 ^ ((b2 & 7) << 4));
                    float ho = 0.f;
                    if (t > 0) {
                        u16 hb_ = *(const u16*)(hst + rb * 32768 + boff);
                        ho = (float)__builtin_bit_cast(_Float16, hb_);
                    }
                    float hn = nv + zv * (ho - nv);
                    *(u16*)(hst + wb * 32768 + boff) = f2h_bits(hn);
                    pdv += hn * l2v[h];
                }
                pd01[rr] = pdv;
            }
            // ---- issue GI loads for mt+1 (gcur consumed above) ----
            if (mt < 3) {
                #pragma unroll
                for (int j = 0; j < 6; ++j) {
                    int NT = (j >> 1) * 16 + 2 * wv + (j & 1);
                    gcur[j] = ld_ring_f4((const u64*)(gis +
                        (((size_t)s * 48 + NT) * 4 + (mt + 1)) * 1024 + l * 16));
                }
            }
            // ---- publish own chunk (L0) / l2-dot partials (L1) ----
            if (!isL1) {
                asm volatile("s_waitcnt lgkmcnt(0)" ::: "memory");
                int b = mt * 16 + (l & 15);
                int boff = (b << 9) + ((((wv << 6) + ((l >> 4) << 4)) ^ ((b & 7) << 4)));
                h8v hv = *(const h8v*)(hst + wb * 32768 + boff);
                st_ring_h8((u64*)(h0c + (((size_t)(s * 8 + wv) * 4 + mt) * 64 + l) * 16), hv);
            } else {
                #pragma unroll
                for (int rr = 0; rr < 4; ++rr) {
                    float v = pd01[rr];
                    v += __shfl_xor(v, 1); v += __shfl_xor(v, 2);
                    v += __shfl_xor(v, 4); v += __shfl_xor(v, 8);
                    pd01[rr] = v;
                }
                if ((l & 15) == 0) {
                    f4v pv = {pd01[0], pd01[1], pd01[2], pd01[3]};
                    *(f4v*)(gpart + ((size_t)t * 8 + wv) * 64 + mt * 16 + (l >> 4) * 4) = pv;
                }
            }
        }
        if (wv == 0 && l == 0) AT_ST(isL1 ? prog1p : prog0p, t);
        __syncthreads();    // h(t) complete in hstage[wb] for all waves
    }
    if (!isL1) {            // flush final h0seq stamp
        asm volatile("s_waitcnt vmcnt(0)" ::: "memory");
        if (l == 0) AT_ST(stHp + ((NNODE - 1) & (RSLOT - 1)) * 8 + wv, NNODE - 1);
    }
}

// ------------------------------- final head --------------------------------
__global__ __launch_bounds__(256)
void head_kernel(const float* __restrict__ gpartg, const float* __restrict__ hdot,
                 const float* __restrict__ l1b, const float* __restrict__ l2b,
                 const float* __restrict__ l3W, const float* __restrict__ l3b,
                 float* __restrict__ out) {
    int idx = blockIdx.x * 256 + threadIdx.x;
    if (idx >= NBATCH * NNODE * 12) return;
    int r = idx / 12, oc = idx - r * 12;
    int b = r >> 9, n = r & 511;
    float g = 0.0f;
    #pragma unroll
    for (int k = 0; k < 8; ++k) g += gpartg[((size_t)n * 8 + k) * 64 + b];
    g += l2b[0];
    float hh = hdot[r] + l1b[0];
    out[idx] = g * l3W[oc] + hh * l3W[12 + oc] + l3b[oc];
}

// ---------------------- static side stream (for capture fork) --------------
static hipStream_t g_side = nullptr;
static hipEvent_t  g_evA  = nullptr;
static hipEvent_t  g_evB  = nullptr;
namespace {
struct SideInit {
    SideInit() {
        if (hipStreamCreateWithFlags(&g_side, hipStreamNonBlocking) != hipSuccess) g_side = nullptr;
        if (hipEventCreateWithFlags(&g_evA, hipEventDisableTiming) != hipSuccess) g_evA = nullptr;
        if (hipEventCreateWithFlags(&g_evB, hipEventDisableTiming) != hipSuccess) g_evB = nullptr;
    }
};
static SideInit g_side_init;
}

// ------------------------------ host launcher ------------------------------
extern "C" void kernel_launch(void* const* d_in, const int* in_sizes, int n_in,
                              void* d_out, int out_size, void* d_ws, size_t ws_size,
                              hipStream_t stream) {
    const float* x    = (const float*)d_in[0];
    const int*   ei   = (const int*)  d_in[1];
    const float* ew   = (const float*)d_in[2];
    const float* Wz   = (const float*)d_in[3];
    const float* bz   = (const float*)d_in[4];
    const float* lzW  = (const float*)d_in[5];
    const float* lzb  = (const float*)d_in[6];
    // d_in[7..10] (TGCN r-gate) unused: H0 == 0
    const float* Wh   = (const float*)d_in[11];
    const float* bh   = (const float*)d_in[12];
    const float* lhW  = (const float*)d_in[13];
    const float* lhb  = (const float*)d_in[14];
    const float* Wih0 = (const float*)d_in[15];
    const float* Whh0 = (const float*)d_in[16];
    const float* bih0 = (const float*)d_in[17];
    const float* bhh0 = (const float*)d_in[18];
    const float* Wih1 = (const float*)d_in[19];
    const float* Whh1 = (const float*)d_in[20];
    const float* bih1 = (const float*)d_in[21];
    const float* bhh1 = (const float*)d_in[22];
    const float* l1W  = (const float*)d_in[23];
    const float* l1b  = (const float*)d_in[24];
    const float* l2W  = (const float*)d_in[25];
    const float* l2b  = (const float*)d_in[26];
    const float* l3W  = (const float*)d_in[27];
    const float* l3b  = (const float*)d_in[28];

    char* ws = (char*)d_ws;
    size_t o = 0;
    auto take = [&](size_t nbytes) {
        char* p = ws + o;
        o = (o + nbytes + 255) & ~(size_t)255;
        return p;
    };
    float* deg    = (float*)take(NNODE * 4);
    float* dinv   = (float*)take(NNODE * 4);
    int*   rowptr = (int*)  take((NNODE + 1) * 4);
    int*   cursor = (int*)  take(NNODE * 4);
    int*   col    = (int*)  take((NEDGE + NNODE) * 4);
    float* val    = (float*)take((NEDGE + NNODE) * 4);
    u16*   Wf     = (u16*)  take((size_t)512 * DCIN * 2);
    float* bfold  = (float*)take(512 * 4);
    float* hdot   = (float*)take((size_t)NBATCH * NNODE * 4);
    float* gpart  = (float*)take((size_t)NNODE * 8 * 64 * 4);            // 1 MB
    u16*   Wpkh   = (u16*)  take((size_t)2 * 8 * 8 * 6 * 64 * 8 * 2);    // 786 KB
    u16*   Wpk0g  = (u16*)  take((size_t)8 * 4 * 6 * 64 * 8 * 2);        // 196 KB
    u16*   Wpk1g  = (u16*)  take((size_t)8 * 8 * 6 * 64 * 8 * 2);        // 393 KB
    u16*   h0seq  = (u16*)  take((size_t)RSLOT * 8 * 4 * 64 * 8 * 2);    // 2 MB
    float* gi0    = (float*)take((size_t)RSLOT * 48 * 4 * 64 * 4 * 4);   // 12.6 MB
    float* gi1    = (float*)take((size_t)RSLOT * 48 * 4 * 64 * 4 * 4);   // 12.6 MB
    int*   syncb  = (int*)  take(8192);
    if (o > ws_size) return;   // clean-failure signature: absmax == 4.57e-2

    const bool fork = (g_side && g_evA && g_evB);
    hipStream_t sideS = fork ? g_side : stream;

    // main: init (deg/counts + stamps/progress to -1)
    init_kernel<<<8, 256, 0, stream>>>(deg, cursor, syncb);

    if (fork) {
        hipEventRecord(g_evA, stream);
        hipStreamWaitEvent(sideS, g_evA, 0);
    }

    // side branch: graph preprocessing -> fold -> TGCN (independent of GRU)
    edge_deg_kernel<<<NEDGE / 256, 256, 0, sideS>>>(ei, ew, deg, cursor);
    scan_kernel<<<1, NNODE, 0, sideS>>>(deg, cursor, dinv, rowptr, cursor, col, val);
    fill_kernel<<<NEDGE / 256, 256, 0, sideS>>>(ei, ew, dinv, cursor, col, val);
    fold_kernel<<<512, DCIN, 0, sideS>>>(Wz, lzW, bz, lzb, Wh, lhW, bh, lhb, Wf, bfold);
    tgcn_kernel<<<512, 256, 0, sideS>>>(x, rowptr, col, val, Wf, bfold, l1W, hdot);
    if (fork) hipEventRecord(g_evB, sideS);

    // main branch: weight repacks -> persistent GRU pipeline
    pack_whh_kernel<<<(2 * 8 * 8 * 6 * 64 + 255) / 256, 256, 0, stream>>>(Whh0, Whh1, Wpkh);
    pack_wih_kernel<<<(8 * 4 * 6 * 64 + 255) / 256, 256, 0, stream>>>(Wih0, DCIN, 4, Wpk0g);
    pack_wih_kernel<<<(8 * 8 * 6 * 64 + 255) / 256, 256, 0, stream>>>(Wih1, DHID, 8, Wpk1g);
    gru_kernel<<<18, 512, 0, stream>>>(x, Wpkh, Wpk0g, Wpk1g, bih0, bhh0,
                                       bih1, bhh1, l2W, h0seq, gi0, gi1,
                                       syncb, gpart);

    // join + head
    if (fork) hipStreamWaitEvent(stream, g_evB, 0);
    head_kernel<<<(NBATCH * NNODE * 12 + 255) / 256, 256, 0, stream>>>(
        gpart, hdot, l1b, l2b, l3W, l3b, (float*)d_out);
    (void)in_sizes; (void)n_in; (void)out_size;
}

// Round 5
// 4581.089 us; speedup vs baseline: 2.8291x; 2.0702x over previous
//
#include <hip/hip_runtime.h>

// ---------------------------------------------------------------------------
// TGCN2 forward, MI355X gfx950. R15 = R13/R14 intra-block recurrence, spill
// fixed BY CONSTRUCTION. 512-thr blocks have a hard 256-reg/wave unified
// budget (2048/8 waves); R13/R14 demand ~290 -> allocator fell to 128+spill
// (WRITE_SIZE 429MB). R15:
//   - BATCH-SPLIT L-blocks: L0a/L0b/L1a/L1b each own 32 batches (recurrence
//     couples channels only -> halves are independent). Halves per-step
//     MFMA+LDS latency; hstage 64->32KB.
//   - Whh: 6 k-chunks in VGPRs (144 regs) + 2 k-chunks in LDS (96KB).
//     Peak demand ~230 < 256.
//   - stH 16 stamps/slot (two L0 halves); feeders/helpers throttle on both
//     consumer halves.
// Producers: 8 feeders (GI0 = x@Wih0^T+b), 8 helpers (GI1 = h0seq@Wih1^T+b),
// 64-slot rings, monotonic stamps, SLACK=56. TGCN branch on side stream (R7).
// ---------------------------------------------------------------------------

typedef unsigned short u16;
typedef unsigned long long u64;
typedef short s8v __attribute__((ext_vector_type(8)));
typedef _Float16 h8v __attribute__((ext_vector_type(8)));
typedef float f4v __attribute__((ext_vector_type(4)));

#define NBATCH 64
#define NNODE  512
#define DCIN   128
#define DHID   256
#define NEDGE  8192
#define RSLOT  64
#define SLACK  56

#define AT_LD(p)   __hip_atomic_load((p), __ATOMIC_RELAXED, __HIP_MEMORY_SCOPE_AGENT)
#define AT_ST(p,v) __hip_atomic_store((p), (v), __ATOMIC_RELAXED, __HIP_MEMORY_SCOPE_AGENT)

__device__ __forceinline__ u16 f2b(float f) {
    union { float f; unsigned int i; } v; v.f = f;
    unsigned int x = v.i;
    return (u16)((x + 0x7FFFu + ((x >> 16) & 1u)) >> 16);   // RNE (TGCN path)
}
__device__ __forceinline__ float sigm(float x)  { return 1.0f / (1.0f + __expf(-x)); }
__device__ __forceinline__ float tanh_(float x) { return 1.0f - 2.0f / (1.0f + __expf(2.0f * x)); }
__device__ __forceinline__ f4v mfma16(s8v a, s8v b, f4v c) {
    return __builtin_amdgcn_mfma_f32_16x16x32_bf16(a, b, c, 0, 0, 0);
}
__device__ __forceinline__ f4v mfma16h(h8v a, h8v b, f4v c) {
    return __builtin_amdgcn_mfma_f32_16x16x32_f16(a, b, c, 0, 0, 0);
}
__device__ __forceinline__ f4v ld_ring_f4(const u64* p) {
    union { u64 d[2]; f4v v; } u;
    u.d[0] = AT_LD(p); u.d[1] = AT_LD(p + 1);
    return u.v;
}
__device__ __forceinline__ void st_ring_f4(u64* p, f4v v) {
    union { f4v v; u64 d[2]; } u; u.v = v;
    AT_ST(p, u.d[0]); AT_ST(p + 1, u.d[1]);
}
__device__ __forceinline__ h8v ld_ring_h8(const u64* p) {
    union { u64 d[2]; h8v v; } u;
    u.d[0] = AT_LD(p); u.d[1] = AT_LD(p + 1);
    return u.v;
}
__device__ __forceinline__ void st_ring_h8(u64* p, h8v v) {
    union { h8v v; u64 d[2]; } u; u.v = v;
    AT_ST(p, u.d[0]); AT_ST(p + 1, u.d[1]);
}
__device__ __forceinline__ u16 f2h_bits(float f) {
    _Float16 h = (_Float16)f;
    return __builtin_bit_cast(u16, h);
}

// --------------------------- graph preprocessing ---------------------------
__global__ void init_kernel(float* deg, int* counts, int* syncb) {
    int i = blockIdx.x * blockDim.x + threadIdx.x;
    if (i < NNODE) { deg[i] = 2.0f; counts[i] = 1; }
    if (i < 4096) syncb[i] = -1;   // prog/progH/stamps: must be < 0
}

__global__ void edge_deg_kernel(const int* __restrict__ ei, const float* __restrict__ ew,
                                float* deg, int* counts) {
    int e = blockIdx.x * blockDim.x + threadIdx.x;
    if (e < NEDGE) {
        int t = ei[NEDGE + e];
        atomicAdd(&deg[t], ew[e]);
        atomicAdd(&counts[t], 1);
    }
}

__global__ void scan_kernel(const float* __restrict__ deg, const int* __restrict__ counts,
                            float* __restrict__ dinv, int* __restrict__ rowptr,
                            int* __restrict__ cursor, int* __restrict__ col,
                            float* __restrict__ val) {
    __shared__ int sc[NNODE];
    int i = threadIdx.x;
    float d = deg[i];
    float di = (d > 0.0f) ? (1.0f / sqrtf(d)) : 0.0f;
    dinv[i] = di;
    int cnt = counts[i];
    sc[i] = cnt;
    __syncthreads();
    for (int ofs = 1; ofs < NNODE; ofs <<= 1) {
        int add = (i >= ofs) ? sc[i - ofs] : 0;
        __syncthreads();
        sc[i] += add;
        __syncthreads();
    }
    int ex = sc[i] - cnt;
    rowptr[i] = ex;
    if (i == NNODE - 1) rowptr[NNODE] = sc[NNODE - 1];
    col[ex] = i;
    val[ex] = di * 2.0f * di;
    cursor[i] = ex + 1;
}

__global__ void fill_kernel(const int* __restrict__ ei, const float* __restrict__ ew,
                            const float* __restrict__ dinv, int* cursor,
                            int* __restrict__ col, float* __restrict__ val) {
    int e = blockIdx.x * blockDim.x + threadIdx.x;
    if (e < NEDGE) {
        int s = ei[e], t = ei[NEDGE + e];
        int p = atomicAdd(&cursor[t], 1);
        col[p] = s;
        val[p] = dinv[s] * ew[e] * dinv[t];
    }
}

// Wf[2j+g][k] = sum_m Wg[k][m]*Lg_top[m][j]; bfold[2j+g] = bg@Lg_top[:,j]+lgb[j]
__global__ void fold_kernel(const float* __restrict__ Wz, const float* __restrict__ lzW,
                            const float* __restrict__ bz, const float* __restrict__ lzb,
                            const float* __restrict__ Wh, const float* __restrict__ lhW,
                            const float* __restrict__ bh, const float* __restrict__ lhb,
                            u16* __restrict__ Wf, float* __restrict__ bfold) {
    int nidx = blockIdx.x;
    int g = nidx & 1, j = nidx >> 1;
    int k = threadIdx.x;
    const float* W = g ? Wh : Wz;
    const float* L = g ? lhW : lzW;
    float acc = 0.0f;
    for (int m = 0; m < DHID; ++m)
        acc += W[k * DHID + m] * L[m * DHID + j];
    Wf[nidx * DCIN + k] = f2b(acc);
    if (k == 0) {
        const float* bg = g ? bh : bz;
        const float* lb = g ? lhb : lzb;
        float ab = 0.0f;
        for (int m = 0; m < DHID; ++m) ab += bg[m] * L[m * DHID + j];
        bfold[nidx] = ab + lb[j];
    }
}

// ----------------------------- weight repacks (f16) ------------------------
// Whh pack: dst[((layer*8+wv)*8+kc)*6+nt][l][e]; wave wv owns h-ch [32wv,32wv+32)
// nt = gate*2+half: ch = gate*256 + wv*32 + half*16 + (l&15); k = kc*32+(l>>4)*8+e
__global__ void pack_whh_kernel(const float* __restrict__ Whh0,
                                const float* __restrict__ Whh1, u16* __restrict__ dst) {
    int id = blockIdx.x * 256 + threadIdx.x;
    if (id >= 2 * 8 * 8 * 6 * 64) return;
    int l = id & 63; int r = id >> 6;
    int nt = r % 6; r /= 6;
    int kc = r % 8; r /= 8;
    int wv = r % 8; r /= 8;
    const float* src = r ? Whh1 : Whh0;
    int ch = (nt >> 1) * 256 + wv * 32 + (nt & 1) * 16 + (l & 15);
    int k0 = kc * 32 + (l >> 4) * 8;
    u16* d = dst + (size_t)id * 8;
    #pragma unroll
    for (int e = 0; e < 8; ++e) d[e] = f2h_bits(src[(size_t)ch * 256 + k0 + e]);
}

// Wih pack: dst[((pb*KC+kc)*6+nt)*64+l][e]; producer pb owns NT [6pb,6pb+6)
__global__ void pack_wih_kernel(const float* __restrict__ W, int K, int KC,
                                u16* __restrict__ dst) {
    int id = blockIdx.x * 256 + threadIdx.x;
    if (id >= 8 * KC * 6 * 64) return;
    int l = id & 63; int r = id >> 6;
    int nt = r % 6; r /= 6;
    int kc = r % KC; r /= KC;
    int pb = r;
    int ch = (pb * 6 + nt) * 16 + (l & 15);
    int k0 = kc * 32 + (l >> 4) * 8;
    u16* d = dst + (size_t)id * 8;
    #pragma unroll
    for (int e = 0; e < 8; ++e) d[e] = f2h_bits(W[(size_t)ch * K + k0 + e]);
}

// --------------- fused TGCN: aggregate + GEMM + cell + l1-dot --------------
__global__ __launch_bounds__(256)
void tgcn_kernel(const float* __restrict__ x, const int* __restrict__ rowptr,
                 const int* __restrict__ col, const float* __restrict__ val,
                 const u16* __restrict__ Wf, const float* __restrict__ bfold,
                 const float* __restrict__ l1W, float* __restrict__ hdot) {
    __shared__ u16 As[64][136];
    const int tid = threadIdx.x;
    const int bx = blockIdx.x;
    const int b = bx >> 3;
    const int n0 = (bx & 7) * 64;
    {
        const int c = tid & 127;
        const int half = tid >> 7;
        for (int it = 0; it < 32; ++it) {
            int r = it * 2 + half;
            int n = n0 + r;
            int s = rowptr[n], e = rowptr[n + 1];
            float acc = 0.0f;
            for (int i = s; i < e; ++i)
                acc += val[i] * x[((size_t)b * NNODE + col[i]) * DCIN + c];
            As[r][c] = f2b(acc);
        }
    }
    __syncthreads();
    const int w = tid >> 6, l = tid & 63;
    const int ncol = l & 15, q = l >> 4, ko = q * 8;
    s8v af[4];
    #pragma unroll
    for (int kc = 0; kc < 4; ++kc)
        af[kc] = *(const s8v*)(&As[w * 16 + ncol][kc * 32 + ko]);
    float partial[4] = {0.f, 0.f, 0.f, 0.f};
    for (int nc = 0; nc < 32; ++nc) {
        int n = nc * 16 + ncol;
        const u16* brow = Wf + (size_t)n * DCIN + ko;
        f4v acc = {0.f, 0.f, 0.f, 0.f};
        #pragma unroll
        for (int kc = 0; kc < 4; ++kc)
            acc = mfma16(af[kc], *(const s8v*)(brow + kc * 32), acc);
        float bias = bfold[n];
        float l1w = l1W[n >> 1];
        #pragma unroll
        for (int rr = 0; rr < 4; ++rr) {
            float v = acc[rr] + bias;
            float o = __shfl_xor(v, 1);
            float zpre = (ncol & 1) ? o : v;
            float hpre = (ncol & 1) ? v : o;
            float hn = (1.0f - sigm(zpre)) * tanh_(hpre);
            hn = hn > 0.0f ? hn : 0.0f;
            if (!(ncol & 1)) partial[rr] += hn * l1w;
        }
    }
    #pragma unroll
    for (int rr = 0; rr < 4; ++rr) {
        float p = partial[rr];
        p += __shfl_xor(p, 1); p += __shfl_xor(p, 2);
        p += __shfl_xor(p, 4); p += __shfl_xor(p, 8);
        if (ncol == 0)
            hdot[bx * 64 + w * 16 + q * 4 + rr] = p;
    }
}

// --------------------- GRU: persistent 20-block pipeline -------------------
// bid 0=L0a, 1=L0b, 2=L1a, 3=L1b (batch halves a: mt0,1 / b: mt2,3),
// bid 4..11 = feeders (GI0 from x), bid 12..19 = helpers (GI1 from h0seq).
// syncb ints: [0..3] prog per L-block, [64..127] progH[hb*8+wv],
//             [128..1151] stH[slot][16] (L0a waves 0..7, L0b waves 8..15),
//             [1152..1663] stG0[slot][pb], [1664..2175] stG1[slot][pb].
// All stamp values = t (init -1).
__global__ __launch_bounds__(512, 2)
void gru_kernel(const float* __restrict__ x,
                const u16* __restrict__ Wpkh, const u16* __restrict__ Wpk0g,
                const u16* __restrict__ Wpk1g,
                const float* __restrict__ bih0, const float* __restrict__ bhh0,
                const float* __restrict__ bih1, const float* __restrict__ bhh1,
                const float* __restrict__ l2W,
                u16* __restrict__ h0seq, float* __restrict__ gi0,
                float* __restrict__ gi1, int* syncb, float* __restrict__ gpart) {
    __shared__ u16 hstage[2][32][256];          // 32KB f16 h ping-pong (32 batches)
    __shared__ u16 whhlds[2][8][6][512];        // 96KB: kc=6,7 Whh chunks

    const int tid = threadIdx.x;
    const int wv = tid >> 6, l = tid & 63;
    const int bid = blockIdx.x;

    int* progLp = syncb;            // [0..3]
    int* progHp = syncb + 64;
    int* stHp   = syncb + 128;      // [slot][16]
    int* stG0   = syncb + 1152;
    int* stG1   = syncb + 1664;
    char* h0c   = (char*)h0seq;

    if (bid >= 4) {
        // ======================= producers =======================
        const bool isF = bid < 12;
        const int pb = isF ? (bid - 4) : (bid - 12);
        const int mt = wv >> 1, g = wv & 1;     // wave -> (M-tile, NT-half)
        const int KC = isF ? 4 : 8;
        h8v wrp[8][3];
        {
            const u16* base = isF ? Wpk0g : Wpk1g;
            #pragma unroll
            for (int kc = 0; kc < 8; ++kc)
                if (kc < KC) {
                    #pragma unroll
                    for (int j = 0; j < 3; ++j)
                        wrp[kc][j] = *(const h8v*)(base +
                            (((size_t)(pb * KC + kc) * 6) + g * 3 + j) * 512 + l * 8);
                }
        }
        float biasp[3];
        const float* bi_ = isF ? bih0 : bih1;
        const float* bh_ = isF ? bhh0 : bhh1;
        #pragma unroll
        for (int j = 0; j < 3; ++j) {
            int NT = pb * 6 + g * 3 + j;
            int gch = NT * 16 + (l & 15);
            biasp[j] = bi_[gch] + (NT < 32 ? bh_[gch] : 0.0f);  // n-gate: bih only
        }
        int* progPair = syncb + (isF ? 0 : 2);  // two consumer halves
        int* mySt   = isF ? stG0 : stG1;
        float* gid  = isF ? gi0 : gi1;

        for (int t = 0; t < NNODE; ++t) {
            int s = t & (RSLOT - 1);
            // ring-overwrite throttle on BOTH consumer halves
            while (true) {
                int v = (l < 2) ? AT_LD(progPair + l) : 0x7fffffff;
                if (__all(v >= t - SLACK)) break;
                __builtin_amdgcn_s_sleep(4);
            }
            h8v A[8];
            if (isF) {
                const float* xp = x + ((size_t)(mt * 16 + (l & 15)) * NNODE + t) * DCIN
                                    + (l >> 4) * 8;
                #pragma unroll
                for (int kc = 0; kc < 4; ++kc) {
                    f4v lo = *(const f4v*)(xp + kc * 32);
                    f4v hi = *(const f4v*)(xp + kc * 32 + 4);
                    h8v a;
                    #pragma unroll
                    for (int e = 0; e < 4; ++e) {
                        a[e] = (_Float16)lo[e]; a[4 + e] = (_Float16)hi[e];
                    }
                    A[kc] = a;
                }
            } else {
                int sv = (l < 16) ? AT_LD(stHp + s * 16 + l) : 0x7fffffff;
                while (!__all(sv >= t)) {
                    __builtin_amdgcn_s_sleep(1);
                    if (l < 16) sv = AT_LD(stHp + s * 16 + l);
                }
                #pragma unroll
                for (int kc = 0; kc < 8; ++kc)
                    A[kc] = ld_ring_h8((const u64*)(h0c +
                        (((size_t)(s * 8 + kc) * 4 + mt) * 64 + l) * 16));
            }
            #pragma unroll
            for (int j = 0; j < 3; ++j) {
                f4v acc = {biasp[j], biasp[j], biasp[j], biasp[j]};
                #pragma unroll
                for (int kc = 0; kc < 8; ++kc)
                    if (kc < KC) acc = mfma16h(A[kc], wrp[kc][j], acc);
                int NT = pb * 6 + g * 3 + j;
                st_ring_f4((u64*)((char*)gid +
                    (((size_t)s * 48 + NT) * 4 + mt) * 1024 + l * 16), acc);
            }
            if (!isF && l == 0) AT_ST(progHp + pb * 8 + wv, t);   // consumed h0(t)
            asm volatile("s_waitcnt vmcnt(0)" ::: "memory");
            __syncthreads();
            if (tid == 0) AT_ST(mySt + s * 8 + pb, t);            // slot complete
        }
        return;
    }

    // ========================= L-blocks (recurrent) =========================
    const bool isL1 = (bid >= 2);
    const int half = bid & 1;                    // batch half: mt = half*2 + mtg
    h8v wr[6][6];                                // Whh kc 0..5 in VGPRs (144)
    #pragma unroll
    for (int kc = 0; kc < 6; ++kc)
        #pragma unroll
        for (int nt = 0; nt < 6; ++nt)
            wr[kc][nt] = *(const h8v*)(Wpkh +
                ((((size_t)(isL1 ? 8 : 0) + wv) * 8 + kc) * 6 + nt) * 512 + l * 8);
    // kc = 6,7 chunks -> LDS (per-wave slices)
    #pragma unroll
    for (int kcx = 0; kcx < 2; ++kcx)
        #pragma unroll
        for (int nt = 0; nt < 6; ++nt)
            *(h8v*)&whhlds[kcx][wv][nt][l * 8] = *(const h8v*)(Wpkh +
                ((((size_t)(isL1 ? 8 : 0) + wv) * 8 + 6 + kcx) * 6 + nt) * 512 + l * 8);
    const float* bhh_ = isL1 ? bhh1 : bhh0;
    float bhn[2], l2v[2];
    #pragma unroll
    for (int h = 0; h < 2; ++h) {
        int ch = wv * 32 + h * 16 + (l & 15);
        bhn[h] = bhh_[512 + ch];
        l2v[h] = isL1 ? l2W[ch] : 0.0f;
    }
    const char* gis = (const char*)(isL1 ? gi1 : gi0);
    int* stG = isL1 ? stG1 : stG0;
    char* hst = (char*)&hstage[0][0][0];

    int stv = (l < 8) ? AT_LD(stG + l) : 0x7fffffff;       // stamps for t=0
    int phv = 0x7fffffff;
    if (!isL1) phv = AT_LD(progHp + l);                     // l<64 always
    f4v gcur[6];
    __syncthreads();

    for (int t = 0; t < NNODE; ++t) {
        const int s = t & (RSLOT - 1);
        const int rb = t & 1, wb = rb ^ 1;
        // GI(t) stamp check (stv prefetched mid previous step)
        while (!__all(stv >= t)) {
            __builtin_amdgcn_s_sleep(1);
            if (l < 8) stv = AT_LD(stG + s * 8 + l);
        }
        if (!isL1) {
            // h0seq(t-1) stamp: all publishes drained (vmem idle here -> cheap)
            if (t > 0) {
                asm volatile("s_waitcnt vmcnt(0)" ::: "memory");
                if (l == 0)
                    AT_ST(stHp + ((t - 1) & (RSLOT - 1)) * 16 + half * 8 + wv, t - 1);
            }
            // ring-overwrite throttle: helpers must be past t-64
            while (!__all(phv >= t - SLACK)) {
                __builtin_amdgcn_s_sleep(1);
                phv = AT_LD(progHp + l);
            }
        }
        // GI loads for mtg0 (consumed at its epilogue, ~full MFMA phase later)
        #pragma unroll
        for (int j = 0; j < 6; ++j) {
            int NT = (j >> 1) * 16 + 2 * wv + (j & 1);
            gcur[j] = ld_ring_f4((const u64*)(gis +
                (((size_t)s * 48 + NT) * 4 + half * 2) * 1024 + l * 16));
        }
        #pragma unroll 1
        for (int mtg = 0; mtg < 2; ++mtg) {
            const int mt = half * 2 + mtg;      // global M-tile
            // mid-step prefetches (off critical path)
            if (mtg == 1 && l < 8 && t + 1 < NNODE)
                stv = AT_LD(stG + ((t + 1) & (RSLOT - 1)) * 8 + l);
            if (mtg == 1 && !isL1)
                phv = AT_LD(progHp + l);
            // ---- gh = h(t-1) @ Whh^T for this M-tile ----
            f4v acc[6];
            #pragma unroll
            for (int nt = 0; nt < 6; ++nt) acc[nt] = (f4v){0.f, 0.f, 0.f, 0.f};
            if (t > 0) {
                const int b = mtg * 16 + (l & 15);   // local batch row
                #pragma unroll
                for (int kc = 0; kc < 6; ++kc) {
                    int boff = (b << 9) + ((((kc << 6) + ((l >> 4) << 4)) ^ ((b & 7) << 4)));
                    h8v A = *(const h8v*)(hst + rb * 16384 + boff);
                    #pragma unroll
                    for (int nt = 0; nt < 6; ++nt)
                        acc[nt] = mfma16h(A, wr[kc][nt], acc[nt]);
                }
                #pragma unroll
                for (int kcx = 0; kcx < 2; ++kcx) {   // kc = 6,7 from LDS
                    int kc = 6 + kcx;
                    int boff = (b << 9) + ((((kc << 6) + ((l >> 4) << 4)) ^ ((b & 7) << 4)));
                    h8v A = *(const h8v*)(hst + rb * 16384 + boff);
                    #pragma unroll
                    for (int nt = 0; nt < 6; ++nt) {
                        h8v wl = *(const h8v*)&whhlds[kcx][wv][nt][l * 8];
                        acc[nt] = mfma16h(A, wl, acc[nt]);
                    }
                }
            }
            // ---- gate epilogue ----
            float pd01[4];
            #pragma unroll
            for (int rr = 0; rr < 4; ++rr) {
                int b2 = mtg * 16 + (l >> 4) * 4 + rr;   // local batch
                float pdv = 0.f;
                #pragma unroll
                for (int h = 0; h < 2; ++h) {
                    float rv = sigm(acc[h][rr] + gcur[h][rr]);
                    float zv = sigm(acc[2 + h][rr] + gcur[2 + h][rr]);
                    float nv = tanh_(gcur[4 + h][rr] + rv * (acc[4 + h][rr] + bhn[h]));
                    int ch2 = (wv * 32 + h * 16 + (l & 15)) * 2;
                    int boff = (b2 << 9) + (ch2 ^ ((b2 & 7) << 4));
                    float ho = 0.f;
                    if (t > 0) {
                        u16 hb_ = *(const u16*)(hst + rb * 16384 + boff);
                        ho = (float)__builtin_bit_cast(_Float16, hb_);
                    }
                    float hn = nv + zv * (ho - nv);
                    *(u16*)(hst + wb * 16384 + boff) = f2h_bits(hn);
                    pdv += hn * l2v[h];
                }
                pd01[rr] = pdv;
            }
            // ---- issue GI loads for mtg+1 (gcur consumed above) ----
            if (mtg < 1) {
                #pragma unroll
                for (int j = 0; j < 6; ++j) {
                    int NT = (j >> 1) * 16 + 2 * wv + (j & 1);
                    gcur[j] = ld_ring_f4((const u64*)(gis +
                        (((size_t)s * 48 + NT) * 4 + half * 2 + 1) * 1024 + l * 16));
                }
            }
            // ---- publish own chunk (L0) / l2-dot partials (L1) ----
            if (!isL1) {
                asm volatile("s_waitcnt lgkmcnt(0)" ::: "memory");
                int b = mtg * 16 + (l & 15);
                int boff = (b << 9) + ((((wv << 6) + ((l >> 4) << 4)) ^ ((b & 7) << 4)));
                h8v hv = *(const h8v*)(hst + wb * 16384 + boff);
                st_ring_h8((u64*)(h0c + (((size_t)(s * 8 + wv) * 4 + mt) * 64 + l) * 16), hv);
            } else {
                #pragma unroll
                for (int rr = 0; rr < 4; ++rr) {
                    float v = pd01[rr];
                    v += __shfl_xor(v, 1); v += __shfl_xor(v, 2);
                    v += __shfl_xor(v, 4); v += __shfl_xor(v, 8);
                    pd01[rr] = v;
                }
                if ((l & 15) == 0) {
                    f4v pv = {pd01[0], pd01[1], pd01[2], pd01[3]};
                    *(f4v*)(gpart + ((size_t)t * 8 + wv) * 64 + mt * 16 + (l >> 4) * 4) = pv;
                }
            }
        }
        if (wv == 0 && l == 0) AT_ST(progLp + bid, t);
        __syncthreads();    // h(t) complete in hstage[wb] for all waves
    }
    if (!isL1) {            // flush final h0seq stamp
        asm volatile("s_waitcnt vmcnt(0)" ::: "memory");
        if (l == 0)
            AT_ST(stHp + ((NNODE - 1) & (RSLOT - 1)) * 16 + half * 8 + wv, NNODE - 1);
    }
}

// ------------------------------- final head --------------------------------
__global__ __launch_bounds__(256)
void head_kernel(const float* __restrict__ gpartg, const float* __restrict__ hdot,
                 const float* __restrict__ l1b, const float* __restrict__ l2b,
                 const float* __restrict__ l3W, const float* __restrict__ l3b,
                 float* __restrict__ out) {
    int idx = blockIdx.x * 256 + threadIdx.x;
    if (idx >= NBATCH * NNODE * 12) return;
    int r = idx / 12, oc = idx - r * 12;
    int b = r >> 9, n = r & 511;
    float g = 0.0f;
    #pragma unroll
    for (int k = 0; k < 8; ++k) g += gpartg[((size_t)n * 8 + k) * 64 + b];
    g += l2b[0];
    float hh = hdot[r] + l1b[0];
    out[idx] = g * l3W[oc] + hh * l3W[12 + oc] + l3b[oc];
}

// ---------------------- static side stream (for capture fork) --------------
static hipStream_t g_side = nullptr;
static hipEvent_t  g_evA  = nullptr;
static hipEvent_t  g_evB  = nullptr;
namespace {
struct SideInit {
    SideInit() {
        if (hipStreamCreateWithFlags(&g_side, hipStreamNonBlocking) != hipSuccess) g_side = nullptr;
        if (hipEventCreateWithFlags(&g_evA, hipEventDisableTiming) != hipSuccess) g_evA = nullptr;
        if (hipEventCreateWithFlags(&g_evB, hipEventDisableTiming) != hipSuccess) g_evB = nullptr;
    }
};
static SideInit g_side_init;
}

// ------------------------------ host launcher ------------------------------
extern "C" void kernel_launch(void* const* d_in, const int* in_sizes, int n_in,
                              void* d_out, int out_size, void* d_ws, size_t ws_size,
                              hipStream_t stream) {
    const float* x    = (const float*)d_in[0];
    const int*   ei   = (const int*)  d_in[1];
    const float* ew   = (const float*)d_in[2];
    const float* Wz   = (const float*)d_in[3];
    const float* bz   = (const float*)d_in[4];
    const float* lzW  = (const float*)d_in[5];
    const float* lzb  = (const float*)d_in[6];
    // d_in[7..10] (TGCN r-gate) unused: H0 == 0
    const float* Wh   = (const float*)d_in[11];
    const float* bh   = (const float*)d_in[12];
    const float* lhW  = (const float*)d_in[13];
    const float* lhb  = (const float*)d_in[14];
    const float* Wih0 = (const float*)d_in[15];
    const float* Whh0 = (const float*)d_in[16];
    const float* bih0 = (const float*)d_in[17];
    const float* bhh0 = (const float*)d_in[18];
    const float* Wih1 = (const float*)d_in[19];
    const float* Whh1 = (const float*)d_in[20];
    const float* bih1 = (const float*)d_in[21];
    const float* bhh1 = (const float*)d_in[22];
    const float* l1W  = (const float*)d_in[23];
    const float* l1b  = (const float*)d_in[24];
    const float* l2W  = (const float*)d_in[25];
    const float* l2b  = (const float*)d_in[26];
    const float* l3W  = (const float*)d_in[27];
    const float* l3b  = (const float*)d_in[28];

    char* ws = (char*)d_ws;
    size_t o = 0;
    auto take = [&](size_t nbytes) {
        char* p = ws + o;
        o = (o + nbytes + 255) & ~(size_t)255;
        return p;
    };
    float* deg    = (float*)take(NNODE * 4);
    float* dinv   = (float*)take(NNODE * 4);
    int*   rowptr = (int*)  take((NNODE + 1) * 4);
    int*   cursor = (int*)  take(NNODE * 4);
    int*   col    = (int*)  take((NEDGE + NNODE) * 4);
    float* val    = (float*)take((NEDGE + NNODE) * 4);
    u16*   Wf     = (u16*)  take((size_t)512 * DCIN * 2);
    float* bfold  = (float*)take(512 * 4);
    float* hdot   = (float*)take((size_t)NBATCH * NNODE * 4);
    float* gpart  = (float*)take((size_t)NNODE * 8 * 64 * 4);            // 1 MB
    u16*   Wpkh   = (u16*)  take((size_t)2 * 8 * 8 * 6 * 64 * 8 * 2);    // 786 KB
    u16*   Wpk0g  = (u16*)  take((size_t)8 * 4 * 6 * 64 * 8 * 2);        // 196 KB
    u16*   Wpk1g  = (u16*)  take((size_t)8 * 8 * 6 * 64 * 8 * 2);        // 393 KB
    u16*   h0seq  = (u16*)  take((size_t)RSLOT * 8 * 4 * 64 * 8 * 2);    // 2 MB
    float* gi0    = (float*)take((size_t)RSLOT * 48 * 4 * 64 * 4 * 4);   // 12.6 MB
    float* gi1    = (float*)take((size_t)RSLOT * 48 * 4 * 64 * 4 * 4);   // 12.6 MB
    int*   syncb  = (int*)  take(16384);
    if (o > ws_size) return;   // clean-failure signature: absmax == 4.57e-2

    const bool fork = (g_side && g_evA && g_evB);
    hipStream_t sideS = fork ? g_side : stream;

    // main: init (deg/counts + stamps/progress to -1)
    init_kernel<<<16, 256, 0, stream>>>(deg, cursor, syncb);

    if (fork) {
        hipEventRecord(g_evA, stream);
        hipStreamWaitEvent(sideS, g_evA, 0);
    }

    // side branch: graph preprocessing -> fold -> TGCN (independent of GRU)
    edge_deg_kernel<<<NEDGE / 256, 256, 0, sideS>>>(ei, ew, deg, cursor);
    scan_kernel<<<1, NNODE, 0, sideS>>>(deg, cursor, dinv, rowptr, cursor, col, val);
    fill_kernel<<<NEDGE / 256, 256, 0, sideS>>>(ei, ew, dinv, cursor, col, val);
    fold_kernel<<<512, DCIN, 0, sideS>>>(Wz, lzW, bz, lzb, Wh, lhW, bh, lhb, Wf, bfold);
    tgcn_kernel<<<512, 256, 0, sideS>>>(x, rowptr, col, val, Wf, bfold, l1W, hdot);
    if (fork) hipEventRecord(g_evB, sideS);

    // main branch: weight repacks -> persistent GRU pipeline
    pack_whh_kernel<<<(2 * 8 * 8 * 6 * 64 + 255) / 256, 256, 0, stream>>>(Whh0, Whh1, Wpkh);
    pack_wih_kernel<<<(8 * 4 * 6 * 64 + 255) / 256, 256, 0, stream>>>(Wih0, DCIN, 4, Wpk0g);
    pack_wih_kernel<<<(8 * 8 * 6 * 64 + 255) / 256, 256, 0, stream>>>(Wih1, DHID, 8, Wpk1g);
    gru_kernel<<<20, 512, 0, stream>>>(x, Wpkh, Wpk0g, Wpk1g, bih0, bhh0,
                                       bih1, bhh1, l2W, h0seq, gi0, gi1,
                                       syncb, gpart);

    // join + head
    if (fork) hipStreamWaitEvent(stream, g_evB, 0);
    head_kernel<<<(NBATCH * NNODE * 12 + 255) / 256, 256, 0, stream>>>(
        gpart, hdot, l1b, l2b, l3W, l3b, (float*)d_out);
    (void)in_sizes; (void)n_in; (void)out_size;
}

// Round 6
// 3769.613 us; speedup vs baseline: 3.4381x; 1.2153x over previous
//
#include <hip/hip_runtime.h>

// ---------------------------------------------------------------------------
// TGCN2 forward, MI355X gfx950. R16 = R15 structure + GROUP-BATCHED sync.
// R15 counter re-read: WRITE_SIZE 429MB == 2x ring data (8B stride-16 atomic
// store pattern), FETCH == ring reads -> NO spill; VGPR_Count=128 is the arch
// half (weights in AGPRs). Remaining cost = per-step cross-block sync chain
// (polls + vmcnt drains + stamps, every step, at 2% occupancy). R16 amortizes
// ALL cross-block sync over groups of G=4 steps:
//   - feeders/helpers: 4 steps/iteration, ONE drain + ONE group stamp;
//   - L0/L1: group-stamp poll once per 4 steps; L0 drains+stamps h0seq once
//     per 4 steps; ring throttles at group frequency;
//   - polls are check-first (no sleep on expected-pass path) + asm memory
//     barrier after each poll.
// Per-step residue: gcur loads + intra-CU MFMA/epilogue + 1 barrier.
// Structure (validated R13..R15, absmax 2.44e-4): L0a/L0b/L1a/L1b own 32
// batches each, h ping-pong in LDS; Whh 6 kc in VGPR/AGPR + 2 kc in LDS;
// 8 feeders (GI0=x@Wih0^T+b), 8 helpers (GI1=h0seq@Wih1^T+b), 64-slot rings.
// TGCN branch unchanged, on side stream (R7).
// ---------------------------------------------------------------------------

typedef unsigned short u16;
typedef unsigned long long u64;
typedef short s8v __attribute__((ext_vector_type(8)));
typedef _Float16 h8v __attribute__((ext_vector_type(8)));
typedef float f4v __attribute__((ext_vector_type(4)));

#define NBATCH 64
#define NNODE  512
#define DCIN   128
#define DHID   256
#define NEDGE  8192
#define RSLOT  64
#define SLACK  56
#define NGRP   (NNODE / 4)

#define AT_LD(p)   __hip_atomic_load((p), __ATOMIC_RELAXED, __HIP_MEMORY_SCOPE_AGENT)
#define AT_ST(p,v) __hip_atomic_store((p), (v), __ATOMIC_RELAXED, __HIP_MEMORY_SCOPE_AGENT)

__device__ __forceinline__ u16 f2b(float f) {
    union { float f; unsigned int i; } v; v.f = f;
    unsigned int x = v.i;
    return (u16)((x + 0x7FFFu + ((x >> 16) & 1u)) >> 16);   // RNE (TGCN path)
}
__device__ __forceinline__ float sigm(float x)  { return 1.0f / (1.0f + __expf(-x)); }
__device__ __forceinline__ float tanh_(float x) { return 1.0f - 2.0f / (1.0f + __expf(2.0f * x)); }
__device__ __forceinline__ f4v mfma16(s8v a, s8v b, f4v c) {
    return __builtin_amdgcn_mfma_f32_16x16x32_bf16(a, b, c, 0, 0, 0);
}
__device__ __forceinline__ f4v mfma16h(h8v a, h8v b, f4v c) {
    return __builtin_amdgcn_mfma_f32_16x16x32_f16(a, b, c, 0, 0, 0);
}
__device__ __forceinline__ f4v ld_ring_f4(const u64* p) {
    union { u64 d[2]; f4v v; } u;
    u.d[0] = AT_LD(p); u.d[1] = AT_LD(p + 1);
    return u.v;
}
__device__ __forceinline__ void st_ring_f4(u64* p, f4v v) {
    union { f4v v; u64 d[2]; } u; u.v = v;
    AT_ST(p, u.d[0]); AT_ST(p + 1, u.d[1]);
}
__device__ __forceinline__ h8v ld_ring_h8(const u64* p) {
    union { u64 d[2]; h8v v; } u;
    u.d[0] = AT_LD(p); u.d[1] = AT_LD(p + 1);
    return u.v;
}
__device__ __forceinline__ void st_ring_h8(u64* p, h8v v) {
    union { h8v v; u64 d[2]; } u; u.v = v;
    AT_ST(p, u.d[0]); AT_ST(p + 1, u.d[1]);
}
__device__ __forceinline__ u16 f2h_bits(float f) {
    _Float16 h = (_Float16)f;
    return __builtin_bit_cast(u16, h);
}

// --------------------------- graph preprocessing ---------------------------
__global__ void init_kernel(float* deg, int* counts, int* syncb) {
    int i = blockIdx.x * blockDim.x + threadIdx.x;
    if (i < NNODE) { deg[i] = 2.0f; counts[i] = 1; }
    if (i < 4096) syncb[i] = -1;   // prog/progH/stamps: must be < 0
}

__global__ void edge_deg_kernel(const int* __restrict__ ei, const float* __restrict__ ew,
                                float* deg, int* counts) {
    int e = blockIdx.x * blockDim.x + threadIdx.x;
    if (e < NEDGE) {
        int t = ei[NEDGE + e];
        atomicAdd(&deg[t], ew[e]);
        atomicAdd(&counts[t], 1);
    }
}

__global__ void scan_kernel(const float* __restrict__ deg, const int* __restrict__ counts,
                            float* __restrict__ dinv, int* __restrict__ rowptr,
                            int* __restrict__ cursor, int* __restrict__ col,
                            float* __restrict__ val) {
    __shared__ int sc[NNODE];
    int i = threadIdx.x;
    float d = deg[i];
    float di = (d > 0.0f) ? (1.0f / sqrtf(d)) : 0.0f;
    dinv[i] = di;
    int cnt = counts[i];
    sc[i] = cnt;
    __syncthreads();
    for (int ofs = 1; ofs < NNODE; ofs <<= 1) {
        int add = (i >= ofs) ? sc[i - ofs] : 0;
        __syncthreads();
        sc[i] += add;
        __syncthreads();
    }
    int ex = sc[i] - cnt;
    rowptr[i] = ex;
    if (i == NNODE - 1) rowptr[NNODE] = sc[NNODE - 1];
    col[ex] = i;
    val[ex] = di * 2.0f * di;
    cursor[i] = ex + 1;
}

__global__ void fill_kernel(const int* __restrict__ ei, const float* __restrict__ ew,
                            const float* __restrict__ dinv, int* cursor,
                            int* __restrict__ col, float* __restrict__ val) {
    int e = blockIdx.x * blockDim.x + threadIdx.x;
    if (e < NEDGE) {
        int s = ei[e], t = ei[NEDGE + e];
        int p = atomicAdd(&cursor[t], 1);
        col[p] = s;
        val[p] = dinv[s] * ew[e] * dinv[t];
    }
}

// Wf[2j+g][k] = sum_m Wg[k][m]*Lg_top[m][j]; bfold[2j+g] = bg@Lg_top[:,j]+lgb[j]
__global__ void fold_kernel(const float* __restrict__ Wz, const float* __restrict__ lzW,
                            const float* __restrict__ bz, const float* __restrict__ lzb,
                            const float* __restrict__ Wh, const float* __restrict__ lhW,
                            const float* __restrict__ bh, const float* __restrict__ lhb,
                            u16* __restrict__ Wf, float* __restrict__ bfold) {
    int nidx = blockIdx.x;
    int g = nidx & 1, j = nidx >> 1;
    int k = threadIdx.x;
    const float* W = g ? Wh : Wz;
    const float* L = g ? lhW : lzW;
    float acc = 0.0f;
    for (int m = 0; m < DHID; ++m)
        acc += W[k * DHID + m] * L[m * DHID + j];
    Wf[nidx * DCIN + k] = f2b(acc);
    if (k == 0) {
        const float* bg = g ? bh : bz;
        const float* lb = g ? lhb : lzb;
        float ab = 0.0f;
        for (int m = 0; m < DHID; ++m) ab += bg[m] * L[m * DHID + j];
        bfold[nidx] = ab + lb[j];
    }
}

// ----------------------------- weight repacks (f16) ------------------------
// Whh pack: dst[((layer*8+wv)*8+kc)*6+nt][l][e]; wave wv owns h-ch [32wv,32wv+32)
__global__ void pack_whh_kernel(const float* __restrict__ Whh0,
                                const float* __restrict__ Whh1, u16* __restrict__ dst) {
    int id = blockIdx.x * 256 + threadIdx.x;
    if (id >= 2 * 8 * 8 * 6 * 64) return;
    int l = id & 63; int r = id >> 6;
    int nt = r % 6; r /= 6;
    int kc = r % 8; r /= 8;
    int wv = r % 8; r /= 8;
    const float* src = r ? Whh1 : Whh0;
    int ch = (nt >> 1) * 256 + wv * 32 + (nt & 1) * 16 + (l & 15);
    int k0 = kc * 32 + (l >> 4) * 8;
    u16* d = dst + (size_t)id * 8;
    #pragma unroll
    for (int e = 0; e < 8; ++e) d[e] = f2h_bits(src[(size_t)ch * 256 + k0 + e]);
}

// Wih pack: dst[((pb*KC+kc)*6+nt)*64+l][e]; producer pb owns NT [6pb,6pb+6)
__global__ void pack_wih_kernel(const float* __restrict__ W, int K, int KC,
                                u16* __restrict__ dst) {
    int id = blockIdx.x * 256 + threadIdx.x;
    if (id >= 8 * KC * 6 * 64) return;
    int l = id & 63; int r = id >> 6;
    int nt = r % 6; r /= 6;
    int kc = r % KC; r /= KC;
    int pb = r;
    int ch = (pb * 6 + nt) * 16 + (l & 15);
    int k0 = kc * 32 + (l >> 4) * 8;
    u16* d = dst + (size_t)id * 8;
    #pragma unroll
    for (int e = 0; e < 8; ++e) d[e] = f2h_bits(W[(size_t)ch * K + k0 + e]);
}

// --------------- fused TGCN: aggregate + GEMM + cell + l1-dot --------------
__global__ __launch_bounds__(256)
void tgcn_kernel(const float* __restrict__ x, const int* __restrict__ rowptr,
                 const int* __restrict__ col, const float* __restrict__ val,
                 const u16* __restrict__ Wf, const float* __restrict__ bfold,
                 const float* __restrict__ l1W, float* __restrict__ hdot) {
    __shared__ u16 As[64][136];
    const int tid = threadIdx.x;
    const int bx = blockIdx.x;
    const int b = bx >> 3;
    const int n0 = (bx & 7) * 64;
    {
        const int c = tid & 127;
        const int half = tid >> 7;
        for (int it = 0; it < 32; ++it) {
            int r = it * 2 + half;
            int n = n0 + r;
            int s = rowptr[n], e = rowptr[n + 1];
            float acc = 0.0f;
            for (int i = s; i < e; ++i)
                acc += val[i] * x[((size_t)b * NNODE + col[i]) * DCIN + c];
            As[r][c] = f2b(acc);
        }
    }
    __syncthreads();
    const int w = tid >> 6, l = tid & 63;
    const int ncol = l & 15, q = l >> 4, ko = q * 8;
    s8v af[4];
    #pragma unroll
    for (int kc = 0; kc < 4; ++kc)
        af[kc] = *(const s8v*)(&As[w * 16 + ncol][kc * 32 + ko]);
    float partial[4] = {0.f, 0.f, 0.f, 0.f};
    for (int nc = 0; nc < 32; ++nc) {
        int n = nc * 16 + ncol;
        const u16* brow = Wf + (size_t)n * DCIN + ko;
        f4v acc = {0.f, 0.f, 0.f, 0.f};
        #pragma unroll
        for (int kc = 0; kc < 4; ++kc)
            acc = mfma16(af[kc], *(const s8v*)(brow + kc * 32), acc);
        float bias = bfold[n];
        float l1w = l1W[n >> 1];
        #pragma unroll
        for (int rr = 0; rr < 4; ++rr) {
            float v = acc[rr] + bias;
            float o = __shfl_xor(v, 1);
            float zpre = (ncol & 1) ? o : v;
            float hpre = (ncol & 1) ? v : o;
            float hn = (1.0f - sigm(zpre)) * tanh_(hpre);
            hn = hn > 0.0f ? hn : 0.0f;
            if (!(ncol & 1)) partial[rr] += hn * l1w;
        }
    }
    #pragma unroll
    for (int rr = 0; rr < 4; ++rr) {
        float p = partial[rr];
        p += __shfl_xor(p, 1); p += __shfl_xor(p, 2);
        p += __shfl_xor(p, 4); p += __shfl_xor(p, 8);
        if (ncol == 0)
            hdot[bx * 64 + w * 16 + q * 4 + rr] = p;
    }
}

// --------------------- GRU: persistent 20-block pipeline -------------------
// bid 0=L0a, 1=L0b, 2=L1a, 3=L1b; bid 4..11 feeders; bid 12..19 helpers.
// syncb: [0..3] progL (steps), [64..127] progH[pb*8+wv] (groups),
//        [128..383] stH[16][16] (groups), [384..511] stG0[16][8],
//        [512..639] stG1[16][8].  Init -1.
__global__ __launch_bounds__(512, 2)
void gru_kernel(const float* __restrict__ x,
                const u16* __restrict__ Wpkh, const u16* __restrict__ Wpk0g,
                const u16* __restrict__ Wpk1g,
                const float* __restrict__ bih0, const float* __restrict__ bhh0,
                const float* __restrict__ bih1, const float* __restrict__ bhh1,
                const float* __restrict__ l2W,
                u16* __restrict__ h0seq, float* __restrict__ gi0,
                float* __restrict__ gi1, int* syncb, float* __restrict__ gpart) {
    __shared__ u16 hstage[2][32][256];          // 32KB f16 h ping-pong (32 batches)
    __shared__ u16 whhlds[2][8][6][512];        // 96KB: kc=6,7 Whh chunks

    const int tid = threadIdx.x;
    const int wv = tid >> 6, l = tid & 63;
    const int bid = blockIdx.x;

    int* progLp = syncb;            // [0..3]
    int* progHp = syncb + 64;
    int* stHp   = syncb + 128;      // [16][16]
    int* stG0   = syncb + 384;      // [16][8]
    int* stG1   = syncb + 512;      // [16][8]
    char* h0c   = (char*)h0seq;

    if (bid >= 4) {
        // ======================= producers (group-batched) =======================
        const bool isF = bid < 12;
        const int pb = isF ? (bid - 4) : (bid - 12);
        const int mt = wv >> 1, gg = wv & 1;    // wave -> (M-tile, NT-half)
        const int KC = isF ? 4 : 8;
        h8v wrp[8][3];
        {
            const u16* base = isF ? Wpk0g : Wpk1g;
            #pragma unroll
            for (int kc = 0; kc < 8; ++kc)
                if (kc < KC) {
                    #pragma unroll
                    for (int j = 0; j < 3; ++j)
                        wrp[kc][j] = *(const h8v*)(base +
                            (((size_t)(pb * KC + kc) * 6) + gg * 3 + j) * 512 + l * 8);
                }
        }
        float biasp[3];
        const float* bi_ = isF ? bih0 : bih1;
        const float* bh_ = isF ? bhh0 : bhh1;
        #pragma unroll
        for (int j = 0; j < 3; ++j) {
            int NT = pb * 6 + gg * 3 + j;
            int gch = NT * 16 + (l & 15);
            biasp[j] = bi_[gch] + (NT < 32 ? bh_[gch] : 0.0f);  // n-gate: bih only
        }
        int* progPair = syncb + (isF ? 0 : 2);  // two consumer halves
        int* mySt   = isF ? stG0 : stG1;
        float* gid  = isF ? gi0 : gi1;

        for (int gr = 0; gr < NGRP; ++gr) {
            // ring-overwrite throttle (both consumer halves), group frequency
            {
                int v = (l < 2) ? AT_LD(progPair + l) : 0x7fffffff;
                while (!__all(v >= 4 * gr - SLACK)) {
                    __builtin_amdgcn_s_sleep(4);
                    v = (l < 2) ? AT_LD(progPair + l) : 0x7fffffff;
                }
            }
            if (!isF) {
                // h0 group availability
                int sv = (l < 16) ? AT_LD(stHp + (gr & 15) * 16 + l) : 0x7fffffff;
                while (!__all(sv >= gr)) {
                    __builtin_amdgcn_s_sleep(1);
                    sv = (l < 16) ? AT_LD(stHp + (gr & 15) * 16 + l) : 0x7fffffff;
                }
            }
            asm volatile("" ::: "memory");
            #pragma unroll 1
            for (int p = 0; p < 2; ++p) {
                #pragma unroll
                for (int jj = 0; jj < 2; ++jj) {
                    const int t = gr * 4 + p * 2 + jj;
                    const int s = t & (RSLOT - 1);
                    h8v A[8];
                    if (isF) {
                        const float* xp = x + ((size_t)(mt * 16 + (l & 15)) * NNODE + t) * DCIN
                                            + (l >> 4) * 8;
                        #pragma unroll
                        for (int kc = 0; kc < 4; ++kc) {
                            f4v lo = *(const f4v*)(xp + kc * 32);
                            f4v hi = *(const f4v*)(xp + kc * 32 + 4);
                            h8v a;
                            #pragma unroll
                            for (int e = 0; e < 4; ++e) {
                                a[e] = (_Float16)lo[e]; a[4 + e] = (_Float16)hi[e];
                            }
                            A[kc] = a;
                        }
                    } else {
                        #pragma unroll
                        for (int kc = 0; kc < 8; ++kc)
                            A[kc] = ld_ring_h8((const u64*)(h0c +
                                (((size_t)(s * 8 + kc) * 4 + mt) * 64 + l) * 16));
                    }
                    #pragma unroll
                    for (int j = 0; j < 3; ++j) {
                        f4v acc = {biasp[j], biasp[j], biasp[j], biasp[j]};
                        #pragma unroll
                        for (int kc = 0; kc < 8; ++kc)
                            if (kc < KC) acc = mfma16h(A[kc], wrp[kc][j], acc);
                        int NT = pb * 6 + gg * 3 + j;
                        st_ring_f4((u64*)((char*)gid +
                            (((size_t)s * 48 + NT) * 4 + mt) * 1024 + l * 16), acc);
                    }
                }
            }
            if (!isF && l == 0) AT_ST(progHp + pb * 8 + wv, gr);  // consumed h0 group
            asm volatile("s_waitcnt vmcnt(0)" ::: "memory");
            __syncthreads();
            if (tid == 0) AT_ST(mySt + (gr & 15) * 8 + pb, gr);   // group complete
        }
        return;
    }

    // ========================= L-blocks (recurrent) =========================
    const bool isL1 = (bid >= 2);
    const int half = bid & 1;                    // batch half: mt = half*2 + mtg
    h8v wr[6][6];                                // Whh kc 0..5 in VGPR/AGPR (144)
    #pragma unroll
    for (int kc = 0; kc < 6; ++kc)
        #pragma unroll
        for (int nt = 0; nt < 6; ++nt)
            wr[kc][nt] = *(const h8v*)(Wpkh +
                ((((size_t)(isL1 ? 8 : 0) + wv) * 8 + kc) * 6 + nt) * 512 + l * 8);
    // kc = 6,7 chunks -> LDS (per-wave slices)
    #pragma unroll
    for (int kcx = 0; kcx < 2; ++kcx)
        #pragma unroll
        for (int nt = 0; nt < 6; ++nt)
            *(h8v*)&whhlds[kcx][wv][nt][l * 8] = *(const h8v*)(Wpkh +
                ((((size_t)(isL1 ? 8 : 0) + wv) * 8 + 6 + kcx) * 6 + nt) * 512 + l * 8);
    const float* bhh_ = isL1 ? bhh1 : bhh0;
    float bhn[2], l2v[2];
    #pragma unroll
    for (int h = 0; h < 2; ++h) {
        int ch = wv * 32 + h * 16 + (l & 15);
        bhn[h] = bhh_[512 + ch];
        l2v[h] = isL1 ? l2W[ch] : 0.0f;
    }
    const char* gis = (const char*)(isL1 ? gi1 : gi0);
    int* stG = isL1 ? stG1 : stG0;
    char* hst = (char*)&hstage[0][0][0];
    f4v gcur[6];
    __syncthreads();

    for (int t = 0; t < NNODE; ++t) {
        const int s = t & (RSLOT - 1);
        const int g = t >> 2, gph = t & 3;
        const int rb = t & 1, wb = rb ^ 1;
        if (gph == 0) {
            // GI group stamp (producers run ahead -> usually first-try)
            int sv = (l < 8) ? AT_LD(stG + (g & 15) * 8 + l) : 0x7fffffff;
            while (!__all(sv >= g)) {
                __builtin_amdgcn_s_sleep(1);
                sv = (l < 8) ? AT_LD(stG + (g & 15) * 8 + l) : 0x7fffffff;
            }
            if (!isL1) {
                // h0seq ring overwrite: helpers must have consumed group g-16
                int ph = AT_LD(progHp + l);
                while (!__all(ph >= g - 15)) {
                    __builtin_amdgcn_s_sleep(1);
                    ph = AT_LD(progHp + l);
                }
            }
            asm volatile("" ::: "memory");
        }
        // GI loads for mtg0 (consumed at its epilogue, ~full MFMA phase later)
        #pragma unroll
        for (int j = 0; j < 6; ++j) {
            int NT = (j >> 1) * 16 + 2 * wv + (j & 1);
            gcur[j] = ld_ring_f4((const u64*)(gis +
                (((size_t)s * 48 + NT) * 4 + half * 2) * 1024 + l * 16));
        }
        #pragma unroll 1
        for (int mtg = 0; mtg < 2; ++mtg) {
            const int mt = half * 2 + mtg;      // global M-tile
            // ---- gh = h(t-1) @ Whh^T for this M-tile ----
            f4v acc[6];
            #pragma unroll
            for (int nt = 0; nt < 6; ++nt) acc[nt] = (f4v){0.f, 0.f, 0.f, 0.f};
            if (t > 0) {
                const int b = mtg * 16 + (l & 15);   // local batch row
                #pragma unroll
                for (int kc = 0; kc < 6; ++kc) {
                    int boff = (b << 9) + ((((kc << 6) + ((l >> 4) << 4)) ^ ((b & 7) << 4)));
                    h8v A = *(const h8v*)(hst + rb * 16384 + boff);
                    #pragma unroll
                    for (int nt = 0; nt < 6; ++nt)
                        acc[nt] = mfma16h(A, wr[kc][nt], acc[nt]);
                }
                #pragma unroll
                for (int kcx = 0; kcx < 2; ++kcx) {   // kc = 6,7 from LDS
                    int kc = 6 + kcx;
                    int boff = (b << 9) + ((((kc << 6) + ((l >> 4) << 4)) ^ ((b & 7) << 4)));
                    h8v A = *(const h8v*)(hst + rb * 16384 + boff);
                    #pragma unroll
                    for (int nt = 0; nt < 6; ++nt) {
                        h8v wl = *(const h8v*)&whhlds[kcx][wv][nt][l * 8];
                        acc[nt] = mfma16h(A, wl, acc[nt]);
                    }
                }
            }
            // ---- gate epilogue ----
            float pd01[4];
            #pragma unroll
            for (int rr = 0; rr < 4; ++rr) {
                int b2 = mtg * 16 + (l >> 4) * 4 + rr;   // local batch
                float pdv = 0.f;
                #pragma unroll
                for (int h = 0; h < 2; ++h) {
                    float rv = sigm(acc[h][rr] + gcur[h][rr]);
                    float zv = sigm(acc[2 + h][rr] + gcur[2 + h][rr]);
                    float nv = tanh_(gcur[4 + h][rr] + rv * (acc[4 + h][rr] + bhn[h]));
                    int ch2 = (wv * 32 + h * 16 + (l & 15)) * 2;
                    int boff = (b2 << 9) + (ch2 ^ ((b2 & 7) << 4));
                    float ho = 0.f;
                    if (t > 0) {
                        u16 hb_ = *(const u16*)(hst + rb * 16384 + boff);
                        ho = (float)__builtin_bit_cast(_Float16, hb_);
                    }
                    float hn = nv + zv * (ho - nv);
                    *(u16*)(hst + wb * 16384 + boff) = f2h_bits(hn);
                    pdv += hn * l2v[h];
                }
                pd01[rr] = pdv;
            }
            // ---- issue GI loads for mtg1 (gcur consumed above) ----
            if (mtg < 1) {
                #pragma unroll
                for (int j = 0; j < 6; ++j) {
                    int NT = (j >> 1) * 16 + 2 * wv + (j & 1);
                    gcur[j] = ld_ring_f4((const u64*)(gis +
                        (((size_t)s * 48 + NT) * 4 + half * 2 + 1) * 1024 + l * 16));
                }
            }
            // ---- publish own chunk (L0) / l2-dot partials (L1) ----
            if (!isL1) {
                asm volatile("s_waitcnt lgkmcnt(0)" ::: "memory");
                int b = mtg * 16 + (l & 15);
                int boff = (b << 9) + ((((wv << 6) + ((l >> 4) << 4)) ^ ((b & 7) << 4)));
                h8v hv = *(const h8v*)(hst + wb * 16384 + boff);
                st_ring_h8((u64*)(h0c + (((size_t)(s * 8 + wv) * 4 + mt) * 64 + l) * 16), hv);
            } else {
                #pragma unroll
                for (int rr = 0; rr < 4; ++rr) {
                    float v = pd01[rr];
                    v += __shfl_xor(v, 1); v += __shfl_xor(v, 2);
                    v += __shfl_xor(v, 4); v += __shfl_xor(v, 8);
                    pd01[rr] = v;
                }
                if ((l & 15) == 0) {
                    f4v pv = {pd01[0], pd01[1], pd01[2], pd01[3]};
                    *(f4v*)(gpart + ((size_t)t * 8 + wv) * 64 + mt * 16 + (l >> 4) * 4) = pv;
                }
            }
        }
        if (wv == 0 && l == 0) AT_ST(progLp + bid, t);
        if (!isL1 && gph == 3) {
            // drain this group's h0 publishes, then per-wave group stamp
            asm volatile("s_waitcnt vmcnt(0)" ::: "memory");
            if (l == 0) AT_ST(stHp + (g & 15) * 16 + half * 8 + wv, g);
        }
        __syncthreads();    // h(t) complete in hstage[wb] for all waves
    }
}

// ------------------------------- final head --------------------------------
__global__ __launch_bounds__(256)
void head_kernel(const float* __restrict__ gpartg, const float* __restrict__ hdot,
                 const float* __restrict__ l1b, const float* __restrict__ l2b,
                 const float* __restrict__ l3W, const float* __restrict__ l3b,
                 float* __restrict__ out) {
    int idx = blockIdx.x * 256 + threadIdx.x;
    if (idx >= NBATCH * NNODE * 12) return;
    int r = idx / 12, oc = idx - r * 12;
    int b = r >> 9, n = r & 511;
    float g = 0.0f;
    #pragma unroll
    for (int k = 0; k < 8; ++k) g += gpartg[((size_t)n * 8 + k) * 64 + b];
    g += l2b[0];
    float hh = hdot[r] + l1b[0];
    out[idx] = g * l3W[oc] + hh * l3W[12 + oc] + l3b[oc];
}

// ---------------------- static side stream (for capture fork) --------------
static hipStream_t g_side = nullptr;
static hipEvent_t  g_evA  = nullptr;
static hipEvent_t  g_evB  = nullptr;
namespace {
struct SideInit {
    SideInit() {
        if (hipStreamCreateWithFlags(&g_side, hipStreamNonBlocking) != hipSuccess) g_side = nullptr;
        if (hipEventCreateWithFlags(&g_evA, hipEventDisableTiming) != hipSuccess) g_evA = nullptr;
        if (hipEventCreateWithFlags(&g_evB, hipEventDisableTiming) != hipSuccess) g_evB = nullptr;
    }
};
static SideInit g_side_init;
}

// ------------------------------ host launcher ------------------------------
extern "C" void kernel_launch(void* const* d_in, const int* in_sizes, int n_in,
                              void* d_out, int out_size, void* d_ws, size_t ws_size,
                              hipStream_t stream) {
    const float* x    = (const float*)d_in[0];
    const int*   ei   = (const int*)  d_in[1];
    const float* ew   = (const float*)d_in[2];
    const float* Wz   = (const float*)d_in[3];
    const float* bz   = (const float*)d_in[4];
    const float* lzW  = (const float*)d_in[5];
    const float* lzb  = (const float*)d_in[6];
    // d_in[7..10] (TGCN r-gate) unused: H0 == 0
    const float* Wh   = (const float*)d_in[11];
    const float* bh   = (const float*)d_in[12];
    const float* lhW  = (const float*)d_in[13];
    const float* lhb  = (const float*)d_in[14];
    const float* Wih0 = (const float*)d_in[15];
    const float* Whh0 = (const float*)d_in[16];
    const float* bih0 = (const float*)d_in[17];
    const float* bhh0 = (const float*)d_in[18];
    const float* Wih1 = (const float*)d_in[19];
    const float* Whh1 = (const float*)d_in[20];
    const float* bih1 = (const float*)d_in[21];
    const float* bhh1 = (const float*)d_in[22];
    const float* l1W  = (const float*)d_in[23];
    const float* l1b  = (const float*)d_in[24];
    const float* l2W  = (const float*)d_in[25];
    const float* l2b  = (const float*)d_in[26];
    const float* l3W  = (const float*)d_in[27];
    const float* l3b  = (const float*)d_in[28];

    char* ws = (char*)d_ws;
    size_t o = 0;
    auto take = [&](size_t nbytes) {
        char* p = ws + o;
        o = (o + nbytes + 255) & ~(size_t)255;
        return p;
    };
    float* deg    = (float*)take(NNODE * 4);
    float* dinv   = (float*)take(NNODE * 4);
    int*   rowptr = (int*)  take((NNODE + 1) * 4);
    int*   cursor = (int*)  take(NNODE * 4);
    int*   col    = (int*)  take((NEDGE + NNODE) * 4);
    float* val    = (float*)take((NEDGE + NNODE) * 4);
    u16*   Wf     = (u16*)  take((size_t)512 * DCIN * 2);
    float* bfold  = (float*)take(512 * 4);
    float* hdot   = (float*)take((size_t)NBATCH * NNODE * 4);
    float* gpart  = (float*)take((size_t)NNODE * 8 * 64 * 4);            // 1 MB
    u16*   Wpkh   = (u16*)  take((size_t)2 * 8 * 8 * 6 * 64 * 8 * 2);    // 786 KB
    u16*   Wpk0g  = (u16*)  take((size_t)8 * 4 * 6 * 64 * 8 * 2);        // 196 KB
    u16*   Wpk1g  = (u16*)  take((size_t)8 * 8 * 6 * 64 * 8 * 2);        // 393 KB
    u16*   h0seq  = (u16*)  take((size_t)RSLOT * 8 * 4 * 64 * 8 * 2);    // 2 MB
    float* gi0    = (float*)take((size_t)RSLOT * 48 * 4 * 64 * 4 * 4);   // 12.6 MB
    float* gi1    = (float*)take((size_t)RSLOT * 48 * 4 * 64 * 4 * 4);   // 12.6 MB
    int*   syncb  = (int*)  take(16384);
    if (o > ws_size) return;   // clean-failure signature: absmax == 4.57e-2

    const bool fork = (g_side && g_evA && g_evB);
    hipStream_t sideS = fork ? g_side : stream;

    // main: init (deg/counts + stamps/progress to -1)
    init_kernel<<<16, 256, 0, stream>>>(deg, cursor, syncb);

    if (fork) {
        hipEventRecord(g_evA, stream);
        hipStreamWaitEvent(sideS, g_evA, 0);
    }

    // side branch: graph preprocessing -> fold -> TGCN (independent of GRU)
    edge_deg_kernel<<<NEDGE / 256, 256, 0, sideS>>>(ei, ew, deg, cursor);
    scan_kernel<<<1, NNODE, 0, sideS>>>(deg, cursor, dinv, rowptr, cursor, col, val);
    fill_kernel<<<NEDGE / 256, 256, 0, sideS>>>(ei, ew, dinv, cursor, col, val);
    fold_kernel<<<512, DCIN, 0, sideS>>>(Wz, lzW, bz, lzb, Wh, lhW, bh, lhb, Wf, bfold);
    tgcn_kernel<<<512, 256, 0, sideS>>>(x, rowptr, col, val, Wf, bfold, l1W, hdot);
    if (fork) hipEventRecord(g_evB, sideS);

    // main branch: weight repacks -> persistent GRU pipeline
    pack_whh_kernel<<<(2 * 8 * 8 * 6 * 64 + 255) / 256, 256, 0, stream>>>(Whh0, Whh1, Wpkh);
    pack_wih_kernel<<<(8 * 4 * 6 * 64 + 255) / 256, 256, 0, stream>>>(Wih0, DCIN, 4, Wpk0g);
    pack_wih_kernel<<<(8 * 8 * 6 * 64 + 255) / 256, 256, 0, stream>>>(Wih1, DHID, 8, Wpk1g);
    gru_kernel<<<20, 512, 0, stream>>>(x, Wpkh, Wpk0g, Wpk1g, bih0, bhh0,
                                       bih1, bhh1, l2W, h0seq, gi0, gi1,
                                       syncb, gpart);

    // join + head
    if (fork) hipStreamWaitEvent(stream, g_evB, 0);
    head_kernel<<<(NBATCH * NNODE * 12 + 255) / 256, 256, 0, stream>>>(
        gpart, hdot, l1b, l2b, l3W, l3b, (float*)d_out);
    (void)in_sizes; (void)n_in; (void)out_size;
}